// Round 10
// baseline (915.908 us; speedup 1.0000x reference)
//
#include <hip/hip_runtime.h>
#include <math.h>

#define GH 256
#define GW 256

typedef float f4 __attribute__((ext_vector_type(4), aligned(4)));
typedef float f2 __attribute__((ext_vector_type(2), aligned(4)));
typedef float f4l __attribute__((ext_vector_type(4)));   // 16B-aligned

template<int CTRL, int RMASK>
__device__ __forceinline__ float dpp_add(float v) {
    int r = __builtin_amdgcn_update_dpp(0, __builtin_bit_cast(int, v), CTRL, RMASK, 0xF, true);
    return v + __builtin_bit_cast(float, r);
}
template<int CTRL, int RMASK>
__device__ __forceinline__ float dpp_max(float v) {
    int r = __builtin_amdgcn_update_dpp(0, __builtin_bit_cast(int, v), CTRL, RMASK, 0xF, true);
    return fmaxf(v, __builtin_bit_cast(float, r));
}
__device__ __forceinline__ float wave_sum63(float v) {
    v = dpp_add<0xB1, 0xF>(v);
    v = dpp_add<0x4E, 0xF>(v);
    v = dpp_add<0x141, 0xF>(v);
    v = dpp_add<0x140, 0xF>(v);
    v = dpp_add<0x142, 0xA>(v);
    v = dpp_add<0x143, 0xC>(v);
    return v;
}
__device__ __forceinline__ float wave_max63(float v) {
    v = dpp_max<0xB1, 0xF>(v);
    v = dpp_max<0x4E, 0xF>(v);
    v = dpp_max<0x141, 0xF>(v);
    v = dpp_max<0x140, 0xF>(v);
    v = dpp_max<0x142, 0xA>(v);
    v = dpp_max<0x143, 0xC>(v);
    return v;
}
__device__ __forceinline__ float rl63(float v) {
    return __builtin_bit_cast(float, __builtin_amdgcn_readlane(__builtin_bit_cast(int, v), 63));
}
__device__ __forceinline__ float frcp(float x)  { return __builtin_amdgcn_rcpf(x); }
__device__ __forceinline__ float frsq(float x)  { return __builtin_amdgcn_rsqf(x); }
__device__ __forceinline__ float fexp2(float x) { return __builtin_amdgcn_exp2f(x); }

// ---------- prep: per-cell {z, gx, gy, fr} with exact edge semantics ----------
__global__ __launch_bounds__(256) void prep_kernel(
    const float* __restrict__ z_grid,
    const float* __restrict__ friction,
    f4* __restrict__ tex)
{
    const int j = threadIdx.x;
    const int i = blockIdx.x;
    const int b = blockIdx.y;
    const float* __restrict__ z = z_grid + (size_t)b * (GH * GW);
    int ipu = (i < GH - 1) ? i + 1 : i;
    int imu = (i > 0) ? i - 1 : i;
    int jpv = (j < GW - 1) ? j + 1 : j;
    int jmv = (j > 0) ? j - 1 : j;
    float scu = (ipu - imu == 2) ? 0.5f : 1.0f;
    float scv = (jpv - jmv == 2) ? 0.5f : 1.0f;
    float gx = ((z[ipu * GW + j] - z[imu * GW + j]) * scu) * 10.0f;
    float gy = ((z[i * GW + jpv] - z[i * GW + jmv]) * scv) * 10.0f;
    f4 o;
    o.x = z[i * GW + j];
    o.y = gx;
    o.z = gy;
    o.w = friction[(size_t)b * (GH * GW) + i * GW + j];
    tex[(size_t)b * (GH * GW) + i * GW + j] = o;
}

// ---------- paired sim kernel: 2 trajectories per block, interleaved ----------
__global__ __launch_bounds__(128) void dphys_kernel2(
    const f4* __restrict__ tex,
    const float* __restrict__ controls,
    const float* __restrict__ robot_points,
    const float* __restrict__ x0,
    const float* __restrict__ xd0,
    const float* __restrict__ R0,
    const float* __restrict__ omega0,
    float* __restrict__ out,
    int T, int B)
{
    const int tid = threadIdx.x;
    const int wv = tid >> 6;
    __shared__ f4l ldsX[2][2][2][2];  // [parity][traj][wave][half]
    __shared__ f4l ldsY[2][2][2];     // [traj][wave][half] slow path / inertia

    int bb0 = blockIdx.x * 2;
    int bb1 = bb0 + 1; if (bb1 >= B) bb1 = B - 1;
    const int bj[2] = {bb0, bb1};

    const f4* tb[2]; const float* ctp[2]; float* obp[2];
    #pragma unroll
    for (int j = 0; j < 2; ++j) {
        tb[j]  = tex + (size_t)bj[j] * (GH * GW);
        ctp[j] = controls + (size_t)bj[j] * (T * 2);
        obp[j] = out + (size_t)bj[j] * (T * 3);
    }

    const float ppx = robot_points[tid * 3 + 0];
    const float ppy = robot_points[tid * 3 + 1];
    const float ppz = robot_points[tid * 3 + 2];
    const bool isL = (ppy < 0.0f);

    // inertia once (robot_points shared across batch)
    float I6[6];
    I6[0] = ppy * ppy + ppz * ppz;
    I6[1] = ppx * ppx + ppz * ppz;
    I6[2] = ppx * ppx + ppy * ppy;
    I6[3] = ppx * ppy;
    I6[4] = ppx * ppz;
    I6[5] = ppy * ppz;
    #pragma unroll
    for (int k = 0; k < 6; ++k) I6[k] = rl63(wave_sum63(I6[k]));
    if ((tid & 63) == 63) {
        f4l t0; t0.x = I6[0]; t0.y = I6[1]; t0.z = I6[2]; t0.w = I6[3];
        f4l t1; t1.x = I6[4]; t1.y = I6[5]; t1.z = 0.f; t1.w = 0.f;
        ldsY[0][wv][0] = t0; ldsY[0][wv][1] = t1;
    }
    __syncthreads();
    {
        f4l o0 = ldsY[0][wv ^ 1][0], o1 = ldsY[0][wv ^ 1][1];
        I6[0] += o0.x; I6[1] += o0.y; I6[2] += o0.z;
        I6[3] += o0.w; I6[4] += o1.x; I6[5] += o1.y;
    }
    const float mp = 0.3125f;
    {
        double a = mp * I6[0], bb = mp * I6[1], c = mp * I6[2];
        double d = -(mp * I6[3]), e = -(mp * I6[4]), f = -(mp * I6[5]);
        double C00 = bb * c - f * f, C01 = e * f - d * c, C02 = d * f - bb * e;
        double C11 = a * c - e * e, C12 = d * e - a * f, C22 = a * bb - d * d;
        double idet = 1.0 / (a * C00 + d * C01 + e * C02);
        I6[0] = (float)(C00 * idet); I6[1] = (float)(C11 * idet); I6[2] = (float)(C22 * idet);
        I6[3] = (float)(C01 * idet); I6[4] = (float)(C02 * idet); I6[5] = (float)(C12 * idet);
    }
    const float i00 = I6[0], i11 = I6[1], i22 = I6[2];
    const float i01 = I6[3], i02 = I6[4], i12 = I6[5];

    // per-trajectory replicated state
    float X0[2], X1[2], X2[2], V0[2], V1[2], V2[2], W0[2], W1[2], W2[2];
    float R00[2], R01[2], R02[2], R10[2], R11[2], R12[2], R20[2], R21[2], R22[2];
    #pragma unroll
    for (int j = 0; j < 2; ++j) {
        int b = bj[j];
        X0[j] = x0[b * 3 + 0]; X1[j] = x0[b * 3 + 1]; X2[j] = x0[b * 3 + 2];
        V0[j] = xd0[b * 3 + 0]; V1[j] = xd0[b * 3 + 1]; V2[j] = xd0[b * 3 + 2];
        W0[j] = omega0[b * 3 + 0]; W1[j] = omega0[b * 3 + 1]; W2[j] = omega0[b * 3 + 2];
        R00[j] = R0[b * 9 + 0]; R01[j] = R0[b * 9 + 1]; R02[j] = R0[b * 9 + 2];
        R10[j] = R0[b * 9 + 3]; R11[j] = R0[b * 9 + 4]; R12[j] = R0[b * 9 + 5];
        R20[j] = R0[b * 9 + 6]; R21[j] = R0[b * 9 + 7]; R22[j] = R0[b * 9 + 8];
    }

    for (int t = 0; t < T; ++t) {
        const int par = t & 1;

        // ---- address phase + loads for BOTH trajectories (8 loads in flight) ----
        float l0[2], l1[2], l2[2], Pz_[2];
        float du_[2], dv_[2];
        f4 c00[2], c01[2], c10[2], c11[2];
        f2 cc[2];
        #pragma unroll
        for (int j = 0; j < 2; ++j) {
            cc[j] = *(const f2*)(ctp[j] + t * 2);
            float rx = R00[j] * ppx + R01[j] * ppy + R02[j] * ppz;
            float ry = R10[j] * ppx + R11[j] * ppy + R12[j] * ppz;
            float rz = R20[j] * ppx + R21[j] * ppy + R22[j] * ppz;
            float Px = rx + X0[j], Py = ry + X1[j], Pz = rz + X2[j];
            l0[j] = Px - X0[j]; l1[j] = Py - X1[j]; l2[j] = Pz - X2[j];
            Pz_[j] = Pz;
            float u = (Px + 12.8f) * 10.0f;
            u = fminf(fmaxf(u, 0.0f), 254.999f);
            float vv = (Py + 12.8f) * 10.0f;
            vv = fminf(fmaxf(vv, 0.0f), 254.999f);
            int u0 = (int)u, v0 = (int)vv;
            du_[j] = u - (float)u0; dv_[j] = vv - (float)v0;
            int idx = (u0 << 8) + v0;
            c00[j] = tb[j][idx];
            c01[j] = tb[j][idx + 1];
            c10[j] = tb[j][idx + GW];
            c11[j] = tb[j][idx + GW + 1];
        }

        // ---- load-shadow work + physics per trajectory ----
        float ic[2], g0[2], g1[2], g2[2], q0[2], q1[2], q2[2], worst[2];
        float mic[2], nxx[2], nyy[2], nzz[2], st0[2], st1[2], st2[2];
        #pragma unroll
        for (int j = 0; j < 2; ++j) {
            float du = du_[j], dv = dv_[j];
            float w00 = (1.0f - du) * (1.0f - dv);
            float w10 = du * (1.0f - dv);
            float w01 = (1.0f - du) * dv;
            float w11 = du * dv;
            float cv = cc[j].x, cw = cc[j].y;
            float half = (cw * 0.6f) * 0.5f;
            float vLs = cv - half, vRs = cv + half;
            float rtn = frsq(R00[j] * R00[j] + R10[j] * R10[j] + R20[j] * R20[j]);
            float th0 = R00[j] * rtn, th1 = R10[j] * rtn, th2 = R20[j] * rtn;
            float xp0 = V0[j] + (W1[j] * l2[j] - W2[j] * l1[j]);
            float xp1 = V1[j] + (W2[j] * l0[j] - W0[j] * l2[j]);
            float xp2 = V2[j] + (W0[j] * l1[j] - W1[j] * l0[j]);
            float cmd = isL ? vLs : vRs;
            float ct0 = cmd * th0 - xp0;
            float ct1 = cmd * th1 - xp1;
            float ct2 = cmd * th2 - xp2;

            f4 cb = c00[j] * w00 + c10[j] * w10 + c01[j] * w01 + c11[j] * w11;
            float zz = cb.x, gxs = cb.y, gys = cb.z, fr = cb.w;

            float rn = frsq(gxs * gxs + gys * gys + 1.0f);
            float nx = -gxs * rn, ny = -gys * rn, nzc = rn;
            float dh = Pz_[j] - zz;
            float ex = fexp2(dh * 14.426950408889634f);
            float icv = frcp(1.0f + ex);
            float xdn = xp0 * nx + xp1 * ny + xp2 * nzc;

            float mag = -(1000.0f * dh + 100.0f * xdn);
            float micv = mag * icv;
            float m_abs = fabsf(micv);
            float sl0 = fr * ct0, sl1 = fr * ct1, sl2 = fr * ct2;
            float sdn = sl0 * nx + sl1 * ny + sl2 * nzc;
            float s0 = sl0 - sdn * nx;
            float s1 = sl1 - sdn * ny;
            float s2 = sl2 - sdn * nzc;
            float gg0 = micv * nx  + m_abs * s0;
            float gg1 = micv * ny  + m_abs * s1;
            float gg2 = micv * nzc + m_abs * s2;
            ic[j] = icv; mic[j] = micv;
            nxx[j] = nx; nyy[j] = ny; nzz[j] = nzc;
            st0[j] = s0; st1[j] = s1; st2[j] = s2;
            g0[j] = gg0; g1[j] = gg1; g2[j] = gg2;
            q0[j] = l1[j] * gg2 - l2[j] * gg1;
            q1[j] = l2[j] * gg0 - l0[j] * gg2;
            q2[j] = l0[j] * gg1 - l1[j] * gg0;
            float stm = fmaxf(fmaxf(fabsf(s0), fabsf(s1)), fabsf(s2));
            worst[j] = fmaxf(stm, 1.0f) * m_abs;
        }

        // ---- 16 sum chains + 2 max chains, one exchange, one barrier ----
        float d_ic[2], d_g0[2], d_g1[2], d_g2[2], d_q0[2], d_q1[2], d_q2[2], d_rw[2];
        #pragma unroll
        for (int j = 0; j < 2; ++j) {
            d_ic[j] = wave_sum63(ic[j]);
            d_g0[j] = wave_sum63(g0[j]);
            d_g1[j] = wave_sum63(g1[j]);
            d_g2[j] = wave_sum63(g2[j]);
            d_q0[j] = wave_sum63(q0[j]);
            d_q1[j] = wave_sum63(q1[j]);
            d_q2[j] = wave_sum63(q2[j]);
            d_rw[j] = wave_max63(worst[j]);
        }
        if ((tid & 63) == 63) {
            #pragma unroll
            for (int j = 0; j < 2; ++j) {
                f4l h0; h0.x = d_g0[j]; h0.y = d_g1[j]; h0.z = d_g2[j]; h0.w = d_q0[j];
                f4l h1; h1.x = d_q1[j]; h1.y = d_q2[j]; h1.z = d_ic[j]; h1.w = d_rw[j];
                ldsX[par][j][wv][0] = h0; ldsX[par][j][wv][1] = h1;
            }
        }
        float o_ic[2], o_g0[2], o_g1[2], o_g2[2], o_q0[2], o_q1[2], o_q2[2], o_rw[2];
        #pragma unroll
        for (int j = 0; j < 2; ++j) {
            o_ic[j] = rl63(d_ic[j]);
            o_g0[j] = rl63(d_g0[j]); o_g1[j] = rl63(d_g1[j]); o_g2[j] = rl63(d_g2[j]);
            o_q0[j] = rl63(d_q0[j]); o_q1[j] = rl63(d_q1[j]); o_q2[j] = rl63(d_q2[j]);
            o_rw[j] = rl63(d_rw[j]);
        }
        __syncthreads();

        #pragma unroll
        for (int j = 0; j < 2; ++j) {
            f4l e0 = ldsX[par][j][wv ^ 1][0], e1 = ldsX[par][j][wv ^ 1][1];
            float sic = o_ic[j] + e1.z;
            float rwm = fmaxf(o_rw[j], e1.w);
            float rsic = frcp(sic);

            float FT0, FT1, FT2, TQ0, TQ1, TQ2;
            if (rwm <= 391.0f * sic) {           // block-uniform per trajectory
                FT0 = (o_g0[j] + e0.x) * rsic;
                FT1 = (o_g1[j] + e0.y) * rsic;
                FT2 = (o_g2[j] + e0.z) * rsic;
                TQ0 = (o_q0[j] + e0.w) * rsic;
                TQ1 = (o_q1[j] + e1.x) * rsic;
                TQ2 = (o_q2[j] + e1.y) * rsic;
            } else {
                float s = mic[j] * rsic;
                float Fr0 = fminf(fmaxf(s * nxx[j], -392.0f), 392.0f);
                float Fr1 = fminf(fmaxf(s * nyy[j], -392.0f), 392.0f);
                float Fr2 = fminf(fmaxf(s * nzz[j], -392.0f), 392.0f);
                float Nm = __builtin_amdgcn_sqrtf(Fr0 * Fr0 + Fr1 * Fr1 + Fr2 * Fr2);
                float Ff0 = fminf(fmaxf(Nm * st0[j], -392.0f), 392.0f);
                float Ff1 = fminf(fmaxf(Nm * st1[j], -392.0f), 392.0f);
                float Ff2 = fminf(fmaxf(Nm * st2[j], -392.0f), 392.0f);
                float S0 = Fr0 + Ff0, S1 = Fr1 + Ff1, S2 = Fr2 + Ff2;
                float U0 = l1[j] * S2 - l2[j] * S1;
                float U1 = l2[j] * S0 - l0[j] * S2;
                float U2 = l0[j] * S1 - l1[j] * S0;
                float dS0 = wave_sum63(S0), dS1 = wave_sum63(S1), dS2 = wave_sum63(S2);
                float dU0 = wave_sum63(U0), dU1 = wave_sum63(U1), dU2 = wave_sum63(U2);
                if ((tid & 63) == 63) {
                    f4l h0; h0.x = dS0; h0.y = dS1; h0.z = dS2; h0.w = dU0;
                    f4l h1; h1.x = dU1; h1.y = dU2; h1.z = 0.f; h1.w = 0.f;
                    ldsY[j][wv][0] = h0; ldsY[j][wv][1] = h1;
                }
                __syncthreads();
                f4l c0 = ldsY[j][wv ^ 1][0], c1 = ldsY[j][wv ^ 1][1];
                FT0 = rl63(dS0) + c0.x; FT1 = rl63(dS1) + c0.y; FT2 = rl63(dS2) + c0.z;
                TQ0 = rl63(dU0) + c0.w; TQ1 = rl63(dU1) + c1.x; TQ2 = rl63(dU2) + c1.y;
            }

            float od0 = fminf(fmaxf(TQ0 * i00 + TQ1 * i01 + TQ2 * i02, -2.0f), 2.0f);
            float od1 = fminf(fmaxf(TQ0 * i01 + TQ1 * i11 + TQ2 * i12, -2.0f), 2.0f);
            float od2 = fminf(fmaxf(TQ0 * i02 + TQ1 * i12 + TQ2 * i22, -2.0f), 2.0f);

            V0[j] += (FT0 * 0.025f) * 0.01f;
            V1[j] += (FT1 * 0.025f) * 0.01f;
            V2[j] += ((-392.0f + FT2) * 0.025f) * 0.01f;
            X0[j] += V0[j] * 0.01f; X1[j] += V1[j] * 0.01f; X2[j] += V2[j] * 0.01f;
            W0[j] += od0 * 0.01f; W1[j] += od1 * 0.01f; W2[j] += od2 * 0.01f;

            if (tid == 0) {
                obp[j][t * 3 + 0] = X0[j];
                obp[j][t * 3 + 1] = X1[j];
                obp[j][t * 3 + 2] = X2[j];
            }

            // polynomial Rodrigues (R7-validated)
            float th2s = W0[j] * W0[j] + W1[j] * W1[j] + W2[j] * W2[j];
            float a2 = th2s * 1e-4f;
            float s1r = 0.01f - a2 * (0.01f / 6.0f);
            float c2r = 5e-5f - a2 * (1e-4f / 24.0f);
            float w01p = W0[j] * W1[j], w02p = W0[j] * W2[j], w12p = W1[j] * W2[j];
            float A00 = 1.0f - c2r * (W1[j] * W1[j] + W2[j] * W2[j]);
            float A11 = 1.0f - c2r * (W0[j] * W0[j] + W2[j] * W2[j]);
            float A22 = 1.0f - c2r * (W0[j] * W0[j] + W1[j] * W1[j]);
            float A01 = c2r * w01p - s1r * W2[j];
            float A10 = c2r * w01p + s1r * W2[j];
            float A02 = c2r * w02p + s1r * W1[j];
            float A20 = c2r * w02p - s1r * W1[j];
            float A12 = c2r * w12p - s1r * W0[j];
            float A21 = c2r * w12p + s1r * W0[j];
            float N00 = R00[j] * A00 + R01[j] * A10 + R02[j] * A20;
            float N01 = R00[j] * A01 + R01[j] * A11 + R02[j] * A21;
            float N02 = R00[j] * A02 + R01[j] * A12 + R02[j] * A22;
            float N10 = R10[j] * A00 + R11[j] * A10 + R12[j] * A20;
            float N11 = R10[j] * A01 + R11[j] * A11 + R12[j] * A21;
            float N12 = R10[j] * A02 + R11[j] * A12 + R12[j] * A22;
            float N20 = R20[j] * A00 + R21[j] * A10 + R22[j] * A20;
            float N21 = R20[j] * A01 + R21[j] * A11 + R22[j] * A21;
            float N22 = R20[j] * A02 + R21[j] * A12 + R22[j] * A22;
            R00[j] = N00; R01[j] = N01; R02[j] = N02;
            R10[j] = N10; R11[j] = N11; R12[j] = N12;
            R20[j] = N20; R21[j] = N21; R22[j] = N22;
        }
    }
}

// ---------- fallback (R7 kernel, used only if ws_size too small) ----------
__global__ __launch_bounds__(128) void dphys_kernel_fb(
    const float* __restrict__ z_grid,
    const float* __restrict__ friction,
    const float* __restrict__ controls,
    const float* __restrict__ robot_points,
    const float* __restrict__ x0,
    const float* __restrict__ xd0,
    const float* __restrict__ R0,
    const float* __restrict__ omega0,
    float* __restrict__ out,
    int T)
{
    const int b = blockIdx.x;
    const int tid = threadIdx.x;
    const int wv = tid >> 6;
    __shared__ f4l ldsX[2][2][2];
    __shared__ f4l ldsY[2][2];

    const float* __restrict__ zg = z_grid + (size_t)b * (GH * GW);
    const float* __restrict__ fg = friction + (size_t)b * (GH * GW);
    const float* __restrict__ ct = controls + (size_t)b * (T * 2);
    float* __restrict__ ob = out + (size_t)b * (T * 3);

    const float ppx = robot_points[tid * 3 + 0];
    const float ppy = robot_points[tid * 3 + 1];
    const float ppz = robot_points[tid * 3 + 2];
    const bool isL = (ppy < 0.0f);

    float I6[6];
    I6[0] = ppy * ppy + ppz * ppz;
    I6[1] = ppx * ppx + ppz * ppz;
    I6[2] = ppx * ppx + ppy * ppy;
    I6[3] = ppx * ppy;
    I6[4] = ppx * ppz;
    I6[5] = ppy * ppz;
    #pragma unroll
    for (int k = 0; k < 6; ++k) I6[k] = rl63(wave_sum63(I6[k]));
    if ((tid & 63) == 63) {
        f4l t0; t0.x = I6[0]; t0.y = I6[1]; t0.z = I6[2]; t0.w = I6[3];
        f4l t1; t1.x = I6[4]; t1.y = I6[5]; t1.z = 0.f; t1.w = 0.f;
        ldsY[wv][0] = t0; ldsY[wv][1] = t1;
    }
    __syncthreads();
    {
        f4l o0 = ldsY[wv ^ 1][0], o1 = ldsY[wv ^ 1][1];
        I6[0] += o0.x; I6[1] += o0.y; I6[2] += o0.z;
        I6[3] += o0.w; I6[4] += o1.x; I6[5] += o1.y;
    }
    const float mp = 0.3125f;
    {
        double a = mp * I6[0], bb = mp * I6[1], c = mp * I6[2];
        double d = -(mp * I6[3]), e = -(mp * I6[4]), f = -(mp * I6[5]);
        double C00 = bb * c - f * f, C01 = e * f - d * c, C02 = d * f - bb * e;
        double C11 = a * c - e * e, C12 = d * e - a * f, C22 = a * bb - d * d;
        double idet = 1.0 / (a * C00 + d * C01 + e * C02);
        I6[0] = (float)(C00 * idet); I6[1] = (float)(C11 * idet); I6[2] = (float)(C22 * idet);
        I6[3] = (float)(C01 * idet); I6[4] = (float)(C02 * idet); I6[5] = (float)(C12 * idet);
    }
    const float i00 = I6[0], i11 = I6[1], i22 = I6[2];
    const float i01 = I6[3], i02 = I6[4], i12 = I6[5];

    float X0 = x0[b * 3 + 0], X1 = x0[b * 3 + 1], X2 = x0[b * 3 + 2];
    float V0 = xd0[b * 3 + 0], V1 = xd0[b * 3 + 1], V2 = xd0[b * 3 + 2];
    float W0 = omega0[b * 3 + 0], W1 = omega0[b * 3 + 1], W2 = omega0[b * 3 + 2];
    float R00 = R0[b * 9 + 0], R01 = R0[b * 9 + 1], R02 = R0[b * 9 + 2];
    float R10 = R0[b * 9 + 3], R11 = R0[b * 9 + 4], R12 = R0[b * 9 + 5];
    float R20 = R0[b * 9 + 6], R21 = R0[b * 9 + 7], R22 = R0[b * 9 + 8];

    for (int t = 0; t < T; ++t) {
        const int par = t & 1;
        f2 cc = *(const f2*)(ct + t * 2);
        float rx = R00 * ppx + R01 * ppy + R02 * ppz;
        float ry = R10 * ppx + R11 * ppy + R12 * ppz;
        float rz = R20 * ppx + R21 * ppy + R22 * ppz;
        float Px = rx + X0, Py = ry + X1, Pz = rz + X2;
        float l0 = Px - X0, l1 = Py - X1, l2 = Pz - X2;
        float u = (Px + 12.8f) * 10.0f;
        u = fminf(fmaxf(u, 0.0f), 254.999f);
        float vvq = (Py + 12.8f) * 10.0f;
        vvq = fminf(fmaxf(vvq, 0.0f), 254.999f);
        int u0 = (int)u, v0 = (int)vvq;
        bool interior = (u0 >= 1) & (u0 <= 253) & (v0 >= 1) & (v0 <= 253);
        bool fastp = __all(interior);

        float zz, fr, gxs, gys;
        float du = u - (float)u0, dv = vvq - (float)v0;
        float w00 = (1.0f - du) * (1.0f - dv);
        float w10 = du * (1.0f - dv);
        float w01 = (1.0f - du) * dv;
        float w11 = du * dv;

        float cv = cc.x, cw = cc.y;
        float half = (cw * 0.6f) * 0.5f;
        float vLs = cv - half, vRs = cv + half;
        float rtn = frsq(R00 * R00 + R10 * R10 + R20 * R20);
        float th0 = R00 * rtn, th1 = R10 * rtn, th2 = R20 * rtn;
        float xp0 = V0 + (W1 * l2 - W2 * l1);
        float xp1 = V1 + (W2 * l0 - W0 * l2);
        float xp2 = V2 + (W0 * l1 - W1 * l0);
        float cmd = isL ? vLs : vRs;
        float ct0 = cmd * th0 - xp0;
        float ct1 = cmd * th1 - xp1;
        float ct2 = cmd * th2 - xp2;

        if (fastp) {
            int base = (u0 - 1) * GW + (v0 - 1);
            f4 P0 = *(const f4*)(zg + base);
            f4 P1 = *(const f4*)(zg + base + GW);
            f4 P2 = *(const f4*)(zg + base + 2 * GW);
            f4 P3 = *(const f4*)(zg + base + 3 * GW);
            int fb = u0 * GW + v0;
            f2 F0 = *(const f2*)(fg + fb);
            f2 F1 = *(const f2*)(fg + fb + GW);
            zz = P1.y * w00 + P2.y * w10 + P1.z * w01 + P2.z * w11;
            fr = F0.x * w00 + F1.x * w10 + F0.y * w01 + F1.y * w11;
            float gx00 = (P2.y - P0.y) * 5.0f;
            float gx10 = (P3.y - P1.y) * 5.0f;
            float gx01 = (P2.z - P0.z) * 5.0f;
            float gx11 = (P3.z - P1.z) * 5.0f;
            float gy00 = (P1.z - P1.x) * 5.0f;
            float gy10 = (P2.z - P2.x) * 5.0f;
            float gy01 = (P1.w - P1.y) * 5.0f;
            float gy11 = (P2.w - P2.y) * 5.0f;
            gxs = gx00 * w00 + gx10 * w10 + gx01 * w01 + gx11 * w11;
            gys = gy00 * w00 + gy10 * w10 + gy01 * w01 + gy11 * w11;
        } else {
            int basei = u0 * GW + v0;
            zz = zg[basei] * w00 + zg[basei + GW] * w10 + zg[basei + 1] * w01 + zg[basei + GW + 1] * w11;
            fr = fg[basei] * w00 + fg[basei + GW] * w10 + fg[basei + 1] * w01 + fg[basei + GW + 1] * w11;
            float gx[2][2], gy[2][2];
            #pragma unroll
            for (int ii = 0; ii < 2; ++ii) {
                int i = u0 + ii;
                int ipu = (i < GH - 1) ? i + 1 : i;
                int imu = (i > 0) ? i - 1 : i;
                float scu = (ipu - imu == 2) ? 0.5f : 1.0f;
                #pragma unroll
                for (int jj = 0; jj < 2; ++jj) {
                    int j = v0 + jj;
                    int jpv = (j < GW - 1) ? j + 1 : j;
                    int jmv = (j > 0) ? j - 1 : j;
                    float scv = (jpv - jmv == 2) ? 0.5f : 1.0f;
                    gx[ii][jj] = ((zg[ipu * GW + j] - zg[imu * GW + j]) * scu) * 10.0f;
                    gy[ii][jj] = ((zg[i * GW + jpv] - zg[i * GW + jmv]) * scv) * 10.0f;
                }
            }
            gxs = gx[0][0] * w00 + gx[1][0] * w10 + gx[0][1] * w01 + gx[1][1] * w11;
            gys = gy[0][0] * w00 + gy[1][0] * w10 + gy[0][1] * w01 + gy[1][1] * w11;
        }

        float rn = frsq(gxs * gxs + gys * gys + 1.0f);
        float nx = -gxs * rn, ny = -gys * rn, nzc = rn;
        float dh = Pz - zz;
        float ex = fexp2(dh * 14.426950408889634f);
        float ic = frcp(1.0f + ex);
        float xdn = xp0 * nx + xp1 * ny + xp2 * nzc;

        float mag = -(1000.0f * dh + 100.0f * xdn);
        float mic = mag * ic;
        float m_abs = fabsf(mic);
        float sl0 = fr * ct0, sl1 = fr * ct1, sl2 = fr * ct2;
        float sdn = sl0 * nx + sl1 * ny + sl2 * nzc;
        float st0 = sl0 - sdn * nx;
        float st1 = sl1 - sdn * ny;
        float st2 = sl2 - sdn * nzc;
        float g0 = mic * nx  + m_abs * st0;
        float g1 = mic * ny  + m_abs * st1;
        float g2 = mic * nzc + m_abs * st2;
        float q0 = l1 * g2 - l2 * g1;
        float q1 = l2 * g0 - l0 * g2;
        float q2 = l0 * g1 - l1 * g0;
        float stm = fmaxf(fmaxf(fabsf(st0), fabsf(st1)), fabsf(st2));
        float worst = fmaxf(stm, 1.0f) * m_abs;

        float d_ic = wave_sum63(ic);
        float d_g0 = wave_sum63(g0), d_g1 = wave_sum63(g1), d_g2 = wave_sum63(g2);
        float d_q0 = wave_sum63(q0), d_q1 = wave_sum63(q1), d_q2 = wave_sum63(q2);
        float d_rw = wave_max63(worst);
        if ((tid & 63) == 63) {
            f4l h0; h0.x = d_g0; h0.y = d_g1; h0.z = d_g2; h0.w = d_q0;
            f4l h1; h1.x = d_q1; h1.y = d_q2; h1.z = d_ic; h1.w = d_rw;
            ldsX[par][wv][0] = h0; ldsX[par][wv][1] = h1;
        }
        float o_ic = rl63(d_ic);
        float o_g0 = rl63(d_g0), o_g1 = rl63(d_g1), o_g2 = rl63(d_g2);
        float o_q0 = rl63(d_q0), o_q1 = rl63(d_q1), o_q2 = rl63(d_q2);
        float o_rw = rl63(d_rw);
        __syncthreads();
        f4l e0 = ldsX[par][wv ^ 1][0], e1 = ldsX[par][wv ^ 1][1];
        float sic = o_ic + e1.z;
        float rwm = fmaxf(o_rw, e1.w);
        float rsic = frcp(sic);

        float FT0, FT1, FT2, TQ0, TQ1, TQ2;
        if (rwm <= 391.0f * sic) {
            FT0 = (o_g0 + e0.x) * rsic;
            FT1 = (o_g1 + e0.y) * rsic;
            FT2 = (o_g2 + e0.z) * rsic;
            TQ0 = (o_q0 + e0.w) * rsic;
            TQ1 = (o_q1 + e1.x) * rsic;
            TQ2 = (o_q2 + e1.y) * rsic;
        } else {
            float s = mic * rsic;
            float Fr0 = fminf(fmaxf(s * nx,  -392.0f), 392.0f);
            float Fr1 = fminf(fmaxf(s * ny,  -392.0f), 392.0f);
            float Fr2 = fminf(fmaxf(s * nzc, -392.0f), 392.0f);
            float Nm = __builtin_amdgcn_sqrtf(Fr0 * Fr0 + Fr1 * Fr1 + Fr2 * Fr2);
            float Ff0 = fminf(fmaxf(Nm * st0, -392.0f), 392.0f);
            float Ff1 = fminf(fmaxf(Nm * st1, -392.0f), 392.0f);
            float Ff2 = fminf(fmaxf(Nm * st2, -392.0f), 392.0f);
            float S0 = Fr0 + Ff0, S1 = Fr1 + Ff1, S2 = Fr2 + Ff2;
            float U0 = l1 * S2 - l2 * S1;
            float U1 = l2 * S0 - l0 * S2;
            float U2 = l0 * S1 - l1 * S0;
            float dS0 = wave_sum63(S0), dS1 = wave_sum63(S1), dS2 = wave_sum63(S2);
            float dU0 = wave_sum63(U0), dU1 = wave_sum63(U1), dU2 = wave_sum63(U2);
            if ((tid & 63) == 63) {
                f4l h0; h0.x = dS0; h0.y = dS1; h0.z = dS2; h0.w = dU0;
                f4l h1; h1.x = dU1; h1.y = dU2; h1.z = 0.f; h1.w = 0.f;
                ldsY[wv][0] = h0; ldsY[wv][1] = h1;
            }
            __syncthreads();
            f4l c0 = ldsY[wv ^ 1][0], c1 = ldsY[wv ^ 1][1];
            FT0 = rl63(dS0) + c0.x; FT1 = rl63(dS1) + c0.y; FT2 = rl63(dS2) + c0.z;
            TQ0 = rl63(dU0) + c0.w; TQ1 = rl63(dU1) + c1.x; TQ2 = rl63(dU2) + c1.y;
        }

        float od0 = fminf(fmaxf(TQ0 * i00 + TQ1 * i01 + TQ2 * i02, -2.0f), 2.0f);
        float od1 = fminf(fmaxf(TQ0 * i01 + TQ1 * i11 + TQ2 * i12, -2.0f), 2.0f);
        float od2 = fminf(fmaxf(TQ0 * i02 + TQ1 * i12 + TQ2 * i22, -2.0f), 2.0f);

        V0 += (FT0 * 0.025f) * 0.01f;
        V1 += (FT1 * 0.025f) * 0.01f;
        V2 += ((-392.0f + FT2) * 0.025f) * 0.01f;
        X0 += V0 * 0.01f; X1 += V1 * 0.01f; X2 += V2 * 0.01f;
        W0 += od0 * 0.01f; W1 += od1 * 0.01f; W2 += od2 * 0.01f;

        if (tid == 0) {
            ob[t * 3 + 0] = X0;
            ob[t * 3 + 1] = X1;
            ob[t * 3 + 2] = X2;
        }

        float th2s = W0 * W0 + W1 * W1 + W2 * W2;
        float a2 = th2s * 1e-4f;
        float s1 = 0.01f - a2 * (0.01f / 6.0f);
        float c2 = 5e-5f - a2 * (1e-4f / 24.0f);
        float w01p = W0 * W1, w02p = W0 * W2, w12p = W1 * W2;
        float A00 = 1.0f - c2 * (W1 * W1 + W2 * W2);
        float A11 = 1.0f - c2 * (W0 * W0 + W2 * W2);
        float A22 = 1.0f - c2 * (W0 * W0 + W1 * W1);
        float A01 = c2 * w01p - s1 * W2;
        float A10 = c2 * w01p + s1 * W2;
        float A02 = c2 * w02p + s1 * W1;
        float A20 = c2 * w02p - s1 * W1;
        float A12 = c2 * w12p - s1 * W0;
        float A21 = c2 * w12p + s1 * W0;
        float N00 = R00 * A00 + R01 * A10 + R02 * A20;
        float N01 = R00 * A01 + R01 * A11 + R02 * A21;
        float N02 = R00 * A02 + R01 * A12 + R02 * A22;
        float N10 = R10 * A00 + R11 * A10 + R12 * A20;
        float N11 = R10 * A01 + R11 * A11 + R12 * A21;
        float N12 = R10 * A02 + R11 * A12 + R12 * A22;
        float N20 = R20 * A00 + R21 * A10 + R22 * A20;
        float N21 = R20 * A01 + R21 * A11 + R22 * A21;
        float N22 = R20 * A02 + R21 * A12 + R22 * A22;
        R00 = N00; R01 = N01; R02 = N02;
        R10 = N10; R11 = N11; R12 = N12;
        R20 = N20; R21 = N21; R22 = N22;
    }
}

extern "C" void kernel_launch(void* const* d_in, const int* in_sizes, int n_in,
                              void* d_out, int out_size, void* d_ws, size_t ws_size,
                              hipStream_t stream) {
    const float* z_grid       = (const float*)d_in[0];
    const float* friction     = (const float*)d_in[1];
    const float* controls     = (const float*)d_in[2];
    const float* robot_points = (const float*)d_in[3];
    const float* x0           = (const float*)d_in[4];
    const float* xd0          = (const float*)d_in[5];
    const float* R0           = (const float*)d_in[6];
    const float* omega0       = (const float*)d_in[7];
    int B = in_sizes[4] / 3;                 // 64
    int T = in_sizes[2] / (B * 2);           // 500
    size_t need = (size_t)B * GH * GW * sizeof(float) * 4;
    if (ws_size >= need) {
        prep_kernel<<<dim3(GH, B), GW, 0, stream>>>(z_grid, friction, (f4*)d_ws);
        int nb = (B + 1) / 2;
        dphys_kernel2<<<nb, 128, 0, stream>>>((const f4*)d_ws, controls, robot_points,
                                              x0, xd0, R0, omega0, (float*)d_out, T, B);
    } else {
        dphys_kernel_fb<<<B, 128, 0, stream>>>(z_grid, friction, controls, robot_points,
                                               x0, xd0, R0, omega0, (float*)d_out, T);
    }
}

// Round 11
// 728.689 us; speedup vs baseline: 1.2569x; 1.2569x over previous
//
#include <hip/hip_runtime.h>
#include <math.h>

#define GH 256
#define GW 256

typedef float f4 __attribute__((ext_vector_type(4), aligned(4)));
typedef float f2 __attribute__((ext_vector_type(2), aligned(4)));
typedef float f4l __attribute__((ext_vector_type(4)));   // 16B-aligned

template<int CTRL, int RMASK>
__device__ __forceinline__ float dpp_add(float v) {
    int r = __builtin_amdgcn_update_dpp(0, __builtin_bit_cast(int, v), CTRL, RMASK, 0xF, true);
    return v + __builtin_bit_cast(float, r);
}
template<int CTRL, int RMASK>
__device__ __forceinline__ float dpp_max(float v) {
    int r = __builtin_amdgcn_update_dpp(0, __builtin_bit_cast(int, v), CTRL, RMASK, 0xF, true);
    return fmaxf(v, __builtin_bit_cast(float, r));
}
__device__ __forceinline__ float wave_sum63(float v) {
    v = dpp_add<0xB1, 0xF>(v);
    v = dpp_add<0x4E, 0xF>(v);
    v = dpp_add<0x141, 0xF>(v);
    v = dpp_add<0x140, 0xF>(v);
    v = dpp_add<0x142, 0xA>(v);
    v = dpp_add<0x143, 0xC>(v);
    return v;
}
__device__ __forceinline__ float wave_max63(float v) {
    v = dpp_max<0xB1, 0xF>(v);
    v = dpp_max<0x4E, 0xF>(v);
    v = dpp_max<0x141, 0xF>(v);
    v = dpp_max<0x140, 0xF>(v);
    v = dpp_max<0x142, 0xA>(v);
    v = dpp_max<0x143, 0xC>(v);
    return v;
}
__device__ __forceinline__ float rl63(float v) {
    return __builtin_bit_cast(float, __builtin_amdgcn_readlane(__builtin_bit_cast(int, v), 63));
}
__device__ __forceinline__ float frcp(float x)  { return __builtin_amdgcn_rcpf(x); }
__device__ __forceinline__ float frsq(float x)  { return __builtin_amdgcn_rsqf(x); }
__device__ __forceinline__ float fexp2(float x) { return __builtin_amdgcn_exp2f(x); }

__device__ __forceinline__ f2 pabs(f2 a)        { f2 r; r.x = fabsf(a.x); r.y = fabsf(a.y); return r; }
__device__ __forceinline__ f2 pmaxv(f2 a, f2 b) { f2 r; r.x = fmaxf(a.x, b.x); r.y = fmaxf(a.y, b.y); return r; }
__device__ __forceinline__ f2 pclamp(f2 a, float lo, float hi) {
    f2 r; r.x = fminf(fmaxf(a.x, lo), hi); r.y = fminf(fmaxf(a.y, lo), hi); return r;
}
__device__ __forceinline__ f2 prsq(f2 a) { f2 r; r.x = frsq(a.x); r.y = frsq(a.y); return r; }

// ---------- prep: per-cell {z, gx, gy, fr} with exact edge semantics ----------
__global__ __launch_bounds__(256) void prep_kernel(
    const float* __restrict__ z_grid,
    const float* __restrict__ friction,
    f4* __restrict__ tex)
{
    const int j = threadIdx.x;
    const int i = blockIdx.x;
    const int b = blockIdx.y;
    const float* __restrict__ z = z_grid + (size_t)b * (GH * GW);
    int ipu = (i < GH - 1) ? i + 1 : i;
    int imu = (i > 0) ? i - 1 : i;
    int jpv = (j < GW - 1) ? j + 1 : j;
    int jmv = (j > 0) ? j - 1 : j;
    float scu = (ipu - imu == 2) ? 0.5f : 1.0f;
    float scv = (jpv - jmv == 2) ? 0.5f : 1.0f;
    float gx = ((z[ipu * GW + j] - z[imu * GW + j]) * scu) * 10.0f;
    float gy = ((z[i * GW + jpv] - z[i * GW + jmv]) * scv) * 10.0f;
    f4 o;
    o.x = z[i * GW + j];
    o.y = gx;
    o.z = gy;
    o.w = friction[(size_t)b * (GH * GW) + i * GW + j];
    tex[(size_t)b * (GH * GW) + i * GW + j] = o;
}

// ---------- packed paired sim kernel: 2 trajectories per block as float2 lanes ----------
__global__ __launch_bounds__(128, 1) void dphys_kernel2p(
    const f4* __restrict__ tex,
    const float* __restrict__ controls,
    const float* __restrict__ robot_points,
    const float* __restrict__ x0,
    const float* __restrict__ xd0,
    const float* __restrict__ R0,
    const float* __restrict__ omega0,
    float* __restrict__ out,
    int T, int B)
{
    const int tid = threadIdx.x;
    const int wv = tid >> 6;
    __shared__ f4l ldsX[2][2][2][2];  // [parity][traj][wave][half]
    __shared__ f4l ldsY[2][2][2];     // [traj][wave][half] slow path / inertia

    int bA = blockIdx.x * 2;
    int bB = bA + 1; if (bB >= B) bB = B - 1;

    const f4* __restrict__ tbA = tex + (size_t)bA * (GH * GW);
    const f4* __restrict__ tbB = tex + (size_t)bB * (GH * GW);
    const float* __restrict__ ctA = controls + (size_t)bA * (T * 2);
    const float* __restrict__ ctB = controls + (size_t)bB * (T * 2);
    float* __restrict__ obA = out + (size_t)bA * (T * 3);
    float* __restrict__ obB = out + (size_t)bB * (T * 3);

    const float ppx = robot_points[tid * 3 + 0];
    const float ppy = robot_points[tid * 3 + 1];
    const float ppz = robot_points[tid * 3 + 2];
    const bool isL = (ppy < 0.0f);

    // inertia once (robot_points shared across batch)
    float I6[6];
    I6[0] = ppy * ppy + ppz * ppz;
    I6[1] = ppx * ppx + ppz * ppz;
    I6[2] = ppx * ppx + ppy * ppy;
    I6[3] = ppx * ppy;
    I6[4] = ppx * ppz;
    I6[5] = ppy * ppz;
    #pragma unroll
    for (int k = 0; k < 6; ++k) I6[k] = rl63(wave_sum63(I6[k]));
    if ((tid & 63) == 63) {
        f4l t0; t0.x = I6[0]; t0.y = I6[1]; t0.z = I6[2]; t0.w = I6[3];
        f4l t1; t1.x = I6[4]; t1.y = I6[5]; t1.z = 0.f; t1.w = 0.f;
        ldsY[0][wv][0] = t0; ldsY[0][wv][1] = t1;
    }
    __syncthreads();
    {
        f4l o0 = ldsY[0][wv ^ 1][0], o1 = ldsY[0][wv ^ 1][1];
        I6[0] += o0.x; I6[1] += o0.y; I6[2] += o0.z;
        I6[3] += o0.w; I6[4] += o1.x; I6[5] += o1.y;
    }
    const float mp = 0.3125f;
    {
        double a = mp * I6[0], bb = mp * I6[1], c = mp * I6[2];
        double d = -(mp * I6[3]), e = -(mp * I6[4]), f = -(mp * I6[5]);
        double C00 = bb * c - f * f, C01 = e * f - d * c, C02 = d * f - bb * e;
        double C11 = a * c - e * e, C12 = d * e - a * f, C22 = a * bb - d * d;
        double idet = 1.0 / (a * C00 + d * C01 + e * C02);
        I6[0] = (float)(C00 * idet); I6[1] = (float)(C11 * idet); I6[2] = (float)(C22 * idet);
        I6[3] = (float)(C01 * idet); I6[4] = (float)(C02 * idet); I6[5] = (float)(C12 * idet);
    }
    const float i00 = I6[0], i11 = I6[1], i22 = I6[2];
    const float i01 = I6[3], i02 = I6[4], i12 = I6[5];

    // packed state: .x = traj A, .y = traj B
    f2 X0, X1, X2, V0, V1, V2, W0, W1, W2;
    f2 R00, R01, R02, R10, R11, R12, R20, R21, R22;
    X0.x = x0[bA*3+0]; X0.y = x0[bB*3+0];
    X1.x = x0[bA*3+1]; X1.y = x0[bB*3+1];
    X2.x = x0[bA*3+2]; X2.y = x0[bB*3+2];
    V0.x = xd0[bA*3+0]; V0.y = xd0[bB*3+0];
    V1.x = xd0[bA*3+1]; V1.y = xd0[bB*3+1];
    V2.x = xd0[bA*3+2]; V2.y = xd0[bB*3+2];
    W0.x = omega0[bA*3+0]; W0.y = omega0[bB*3+0];
    W1.x = omega0[bA*3+1]; W1.y = omega0[bB*3+1];
    W2.x = omega0[bA*3+2]; W2.y = omega0[bB*3+2];
    R00.x = R0[bA*9+0]; R00.y = R0[bB*9+0];
    R01.x = R0[bA*9+1]; R01.y = R0[bB*9+1];
    R02.x = R0[bA*9+2]; R02.y = R0[bB*9+2];
    R10.x = R0[bA*9+3]; R10.y = R0[bB*9+3];
    R11.x = R0[bA*9+4]; R11.y = R0[bB*9+4];
    R12.x = R0[bA*9+5]; R12.y = R0[bB*9+5];
    R20.x = R0[bA*9+6]; R20.y = R0[bB*9+6];
    R21.x = R0[bA*9+7]; R21.y = R0[bB*9+7];
    R22.x = R0[bA*9+8]; R22.y = R0[bB*9+8];

    for (int t = 0; t < T; ++t) {
        const int par = t & 1;
        f2 ccA = *(const f2*)(ctA + t * 2);
        f2 ccB = *(const f2*)(ctB + t * 2);
        f2 cv; cv.x = ccA.x; cv.y = ccB.x;
        f2 cw; cw.x = ccA.y; cw.y = ccB.y;

        // ---- address phase (packed), loads for both trajectories issued together ----
        f2 rx = R00 * ppx + R01 * ppy + R02 * ppz;
        f2 ry = R10 * ppx + R11 * ppy + R12 * ppz;
        f2 rz = R20 * ppx + R21 * ppy + R22 * ppz;
        f2 Px = rx + X0, Py = ry + X1, Pz = rz + X2;
        f2 l0 = Px - X0, l1 = Py - X1, l2 = Pz - X2;
        f2 u = pclamp((Px + 12.8f) * 10.0f, 0.0f, 254.999f);
        f2 vq = pclamp((Py + 12.8f) * 10.0f, 0.0f, 254.999f);
        int u0A = (int)u.x, u0B = (int)u.y;
        int v0A = (int)vq.x, v0B = (int)vq.y;
        f2 du; du.x = u.x - (float)u0A; du.y = u.y - (float)u0B;
        f2 dv; dv.x = vq.x - (float)v0A; dv.y = vq.y - (float)v0B;
        int idxA = (u0A << 8) + v0A;
        int idxB = (u0B << 8) + v0B;
        f4 a00 = tbA[idxA], a01 = tbA[idxA + 1], a10 = tbA[idxA + GW], a11 = tbA[idxA + GW + 1];
        f4 b00 = tbB[idxB], b01 = tbB[idxB + 1], b10 = tbB[idxB + GW], b11 = tbB[idxB + GW + 1];

        // ---- load-shadow work (packed) ----
        f2 half_ = (cw * 0.6f) * 0.5f;
        f2 vLs = cv - half_, vRs = cv + half_;
        f2 rtn = prsq(R00 * R00 + R10 * R10 + R20 * R20);
        f2 th0 = R00 * rtn, th1 = R10 * rtn, th2 = R20 * rtn;
        f2 xp0 = V0 + (W1 * l2 - W2 * l1);
        f2 xp1 = V1 + (W2 * l0 - W0 * l2);
        f2 xp2 = V2 + (W0 * l1 - W1 * l0);
        f2 cmd = isL ? vLs : vRs;
        f2 ct0 = cmd * th0 - xp0;
        f2 ct1 = cmd * th1 - xp1;
        f2 ct2 = cmd * th2 - xp2;

        // ---- bilinear blends (per-traj f4, independent streams) ----
        float w00A = (1.0f - du.x) * (1.0f - dv.x);
        float w10A = du.x * (1.0f - dv.x);
        float w01A = (1.0f - du.x) * dv.x;
        float w11A = du.x * dv.x;
        float w00B = (1.0f - du.y) * (1.0f - dv.y);
        float w10B = du.y * (1.0f - dv.y);
        float w01B = (1.0f - du.y) * dv.y;
        float w11B = du.y * dv.y;
        f4 cbA = a00 * w00A + a10 * w10A + a01 * w01A + a11 * w11A;
        f4 cbB = b00 * w00B + b10 * w10B + b01 * w01B + b11 * w11B;
        f2 zz;  zz.x = cbA.x;  zz.y = cbB.x;
        f2 gxs; gxs.x = cbA.y; gxs.y = cbB.y;
        f2 gys; gys.x = cbA.z; gys.y = cbB.z;
        f2 fr;  fr.x = cbA.w;  fr.y = cbB.w;

        // ---- physics (packed) ----
        f2 rn = prsq(gxs * gxs + gys * gys + 1.0f);
        f2 nx = -gxs * rn, ny = -gys * rn, nz = rn;
        f2 dh = Pz - zz;
        f2 ex; ex.x = fexp2(dh.x * 14.426950408889634f); ex.y = fexp2(dh.y * 14.426950408889634f);
        f2 ic; ic.x = frcp(1.0f + ex.x); ic.y = frcp(1.0f + ex.y);
        f2 xdn = xp0 * nx + xp1 * ny + xp2 * nz;

        f2 mag = -(1000.0f * dh + 100.0f * xdn);
        f2 mic = mag * ic;
        f2 m_abs = pabs(mic);
        f2 sl0 = fr * ct0, sl1 = fr * ct1, sl2 = fr * ct2;
        f2 sdn = sl0 * nx + sl1 * ny + sl2 * nz;
        f2 st0 = sl0 - sdn * nx;
        f2 st1 = sl1 - sdn * ny;
        f2 st2 = sl2 - sdn * nz;
        f2 g0 = mic * nx + m_abs * st0;
        f2 g1 = mic * ny + m_abs * st1;
        f2 g2 = mic * nz + m_abs * st2;
        f2 q0 = l1 * g2 - l2 * g1;
        f2 q1 = l2 * g0 - l0 * g2;
        f2 q2 = l0 * g1 - l1 * g0;
        f2 stm = pmaxv(pmaxv(pabs(st0), pabs(st1)), pabs(st2));
        f2 one; one.x = 1.0f; one.y = 1.0f;
        f2 worst = pmaxv(stm, one) * m_abs;

        // ---- 16 sum chains + 2 max chains (independent, pipelined) ----
        float d_icA = wave_sum63(ic.x), d_icB = wave_sum63(ic.y);
        float d_g0A = wave_sum63(g0.x), d_g0B = wave_sum63(g0.y);
        float d_g1A = wave_sum63(g1.x), d_g1B = wave_sum63(g1.y);
        float d_g2A = wave_sum63(g2.x), d_g2B = wave_sum63(g2.y);
        float d_q0A = wave_sum63(q0.x), d_q0B = wave_sum63(q0.y);
        float d_q1A = wave_sum63(q1.x), d_q1B = wave_sum63(q1.y);
        float d_q2A = wave_sum63(q2.x), d_q2B = wave_sum63(q2.y);
        float d_rwA = wave_max63(worst.x), d_rwB = wave_max63(worst.y);
        if ((tid & 63) == 63) {
            f4l h0; h0.x = d_g0A; h0.y = d_g1A; h0.z = d_g2A; h0.w = d_q0A;
            f4l h1; h1.x = d_q1A; h1.y = d_q2A; h1.z = d_icA; h1.w = d_rwA;
            ldsX[par][0][wv][0] = h0; ldsX[par][0][wv][1] = h1;
            f4l h2; h2.x = d_g0B; h2.y = d_g1B; h2.z = d_g2B; h2.w = d_q0B;
            f4l h3; h3.x = d_q1B; h3.y = d_q2B; h3.z = d_icB; h3.w = d_rwB;
            ldsX[par][1][wv][0] = h2; ldsX[par][1][wv][1] = h3;
        }
        float o_icA = rl63(d_icA), o_icB = rl63(d_icB);
        float o_g0A = rl63(d_g0A), o_g0B = rl63(d_g0B);
        float o_g1A = rl63(d_g1A), o_g1B = rl63(d_g1B);
        float o_g2A = rl63(d_g2A), o_g2B = rl63(d_g2B);
        float o_q0A = rl63(d_q0A), o_q0B = rl63(d_q0B);
        float o_q1A = rl63(d_q1A), o_q1B = rl63(d_q1B);
        float o_q2A = rl63(d_q2A), o_q2B = rl63(d_q2B);
        float o_rwA = rl63(d_rwA), o_rwB = rl63(d_rwB);
        __syncthreads();

        f4l e0A = ldsX[par][0][wv ^ 1][0], e1A = ldsX[par][0][wv ^ 1][1];
        f4l e0B = ldsX[par][1][wv ^ 1][0], e1B = ldsX[par][1][wv ^ 1][1];
        float sicA = o_icA + e1A.z, sicB = o_icB + e1B.z;
        float rwmA = fmaxf(o_rwA, e1A.w), rwmB = fmaxf(o_rwB, e1B.w);
        float rsicA = frcp(sicA), rsicB = frcp(sicB);

        f2 FT0, FT1, FT2, TQ0, TQ1, TQ2;
        FT0.x = (o_g0A + e0A.x) * rsicA; FT0.y = (o_g0B + e0B.x) * rsicB;
        FT1.x = (o_g1A + e0A.y) * rsicA; FT1.y = (o_g1B + e0B.y) * rsicB;
        FT2.x = (o_g2A + e0A.z) * rsicA; FT2.y = (o_g2B + e0B.z) * rsicB;
        TQ0.x = (o_q0A + e0A.w) * rsicA; TQ0.y = (o_q0B + e0B.w) * rsicB;
        TQ1.x = (o_q1A + e1A.x) * rsicA; TQ1.y = (o_q1B + e1B.x) * rsicB;
        TQ2.x = (o_q2A + e1A.y) * rsicA; TQ2.y = (o_q2B + e1B.y) * rsicB;

        // exact slow path per trajectory (rare; block-uniform conditions)
        if (rwmA > 391.0f * sicA) {
            float s = mic.x * rsicA;
            float Fr0 = fminf(fmaxf(s * nx.x, -392.0f), 392.0f);
            float Fr1 = fminf(fmaxf(s * ny.x, -392.0f), 392.0f);
            float Fr2 = fminf(fmaxf(s * nz.x, -392.0f), 392.0f);
            float Nm = __builtin_amdgcn_sqrtf(Fr0 * Fr0 + Fr1 * Fr1 + Fr2 * Fr2);
            float Ff0 = fminf(fmaxf(Nm * st0.x, -392.0f), 392.0f);
            float Ff1 = fminf(fmaxf(Nm * st1.x, -392.0f), 392.0f);
            float Ff2 = fminf(fmaxf(Nm * st2.x, -392.0f), 392.0f);
            float S0 = Fr0 + Ff0, S1 = Fr1 + Ff1, S2 = Fr2 + Ff2;
            float U0 = l1.x * S2 - l2.x * S1;
            float U1 = l2.x * S0 - l0.x * S2;
            float U2 = l0.x * S1 - l1.x * S0;
            float dS0 = wave_sum63(S0), dS1 = wave_sum63(S1), dS2 = wave_sum63(S2);
            float dU0 = wave_sum63(U0), dU1 = wave_sum63(U1), dU2 = wave_sum63(U2);
            if ((tid & 63) == 63) {
                f4l h0; h0.x = dS0; h0.y = dS1; h0.z = dS2; h0.w = dU0;
                f4l h1; h1.x = dU1; h1.y = dU2; h1.z = 0.f; h1.w = 0.f;
                ldsY[0][wv][0] = h0; ldsY[0][wv][1] = h1;
            }
            __syncthreads();
            f4l c0 = ldsY[0][wv ^ 1][0], c1 = ldsY[0][wv ^ 1][1];
            FT0.x = rl63(dS0) + c0.x; FT1.x = rl63(dS1) + c0.y; FT2.x = rl63(dS2) + c0.z;
            TQ0.x = rl63(dU0) + c0.w; TQ1.x = rl63(dU1) + c1.x; TQ2.x = rl63(dU2) + c1.y;
        }
        if (rwmB > 391.0f * sicB) {
            float s = mic.y * rsicB;
            float Fr0 = fminf(fmaxf(s * nx.y, -392.0f), 392.0f);
            float Fr1 = fminf(fmaxf(s * ny.y, -392.0f), 392.0f);
            float Fr2 = fminf(fmaxf(s * nz.y, -392.0f), 392.0f);
            float Nm = __builtin_amdgcn_sqrtf(Fr0 * Fr0 + Fr1 * Fr1 + Fr2 * Fr2);
            float Ff0 = fminf(fmaxf(Nm * st0.y, -392.0f), 392.0f);
            float Ff1 = fminf(fmaxf(Nm * st1.y, -392.0f), 392.0f);
            float Ff2 = fminf(fmaxf(Nm * st2.y, -392.0f), 392.0f);
            float S0 = Fr0 + Ff0, S1 = Fr1 + Ff1, S2 = Fr2 + Ff2;
            float U0 = l1.y * S2 - l2.y * S1;
            float U1 = l2.y * S0 - l0.y * S2;
            float U2 = l0.y * S1 - l1.y * S0;
            float dS0 = wave_sum63(S0), dS1 = wave_sum63(S1), dS2 = wave_sum63(S2);
            float dU0 = wave_sum63(U0), dU1 = wave_sum63(U1), dU2 = wave_sum63(U2);
            if ((tid & 63) == 63) {
                f4l h0; h0.x = dS0; h0.y = dS1; h0.z = dS2; h0.w = dU0;
                f4l h1; h1.x = dU1; h1.y = dU2; h1.z = 0.f; h1.w = 0.f;
                ldsY[1][wv][0] = h0; ldsY[1][wv][1] = h1;
            }
            __syncthreads();
            f4l c0 = ldsY[1][wv ^ 1][0], c1 = ldsY[1][wv ^ 1][1];
            FT0.y = rl63(dS0) + c0.x; FT1.y = rl63(dS1) + c0.y; FT2.y = rl63(dS2) + c0.z;
            TQ0.y = rl63(dU0) + c0.w; TQ1.y = rl63(dU1) + c1.x; TQ2.y = rl63(dU2) + c1.y;
        }

        // ---- packed tail ----
        f2 od0 = pclamp(TQ0 * i00 + TQ1 * i01 + TQ2 * i02, -2.0f, 2.0f);
        f2 od1 = pclamp(TQ0 * i01 + TQ1 * i11 + TQ2 * i12, -2.0f, 2.0f);
        f2 od2 = pclamp(TQ0 * i02 + TQ1 * i12 + TQ2 * i22, -2.0f, 2.0f);

        V0 += (FT0 * 0.025f) * 0.01f;
        V1 += (FT1 * 0.025f) * 0.01f;
        V2 += ((FT2 - 392.0f) * 0.025f) * 0.01f;
        X0 += V0 * 0.01f; X1 += V1 * 0.01f; X2 += V2 * 0.01f;
        W0 += od0 * 0.01f; W1 += od1 * 0.01f; W2 += od2 * 0.01f;

        if (tid == 0) {
            obA[t * 3 + 0] = X0.x; obA[t * 3 + 1] = X1.x; obA[t * 3 + 2] = X2.x;
            obB[t * 3 + 0] = X0.y; obB[t * 3 + 1] = X1.y; obB[t * 3 + 2] = X2.y;
        }

        // polynomial Rodrigues (R7-validated), packed
        f2 th2s = W0 * W0 + W1 * W1 + W2 * W2;
        f2 a2 = th2s * 1e-4f;
        f2 s1 = 0.01f - a2 * (0.01f / 6.0f);
        f2 c2 = 5e-5f - a2 * (1e-4f / 24.0f);
        f2 w01p = W0 * W1, w02p = W0 * W2, w12p = W1 * W2;
        f2 A00 = 1.0f - c2 * (W1 * W1 + W2 * W2);
        f2 A11 = 1.0f - c2 * (W0 * W0 + W2 * W2);
        f2 A22 = 1.0f - c2 * (W0 * W0 + W1 * W1);
        f2 A01 = c2 * w01p - s1 * W2;
        f2 A10 = c2 * w01p + s1 * W2;
        f2 A02 = c2 * w02p + s1 * W1;
        f2 A20 = c2 * w02p - s1 * W1;
        f2 A12 = c2 * w12p - s1 * W0;
        f2 A21 = c2 * w12p + s1 * W0;
        f2 N00 = R00 * A00 + R01 * A10 + R02 * A20;
        f2 N01 = R00 * A01 + R01 * A11 + R02 * A21;
        f2 N02 = R00 * A02 + R01 * A12 + R02 * A22;
        f2 N10 = R10 * A00 + R11 * A10 + R12 * A20;
        f2 N11 = R10 * A01 + R11 * A11 + R12 * A21;
        f2 N12 = R10 * A02 + R11 * A12 + R12 * A22;
        f2 N20 = R20 * A00 + R21 * A10 + R22 * A20;
        f2 N21 = R20 * A01 + R21 * A11 + R22 * A21;
        f2 N22 = R20 * A02 + R21 * A12 + R22 * A22;
        R00 = N00; R01 = N01; R02 = N02;
        R10 = N10; R11 = N11; R12 = N12;
        R20 = N20; R21 = N21; R22 = N22;
    }
}

// ---------- fallback (no-workspace path; R7 structure) ----------
__global__ __launch_bounds__(128) void dphys_kernel_fb(
    const float* __restrict__ z_grid,
    const float* __restrict__ friction,
    const float* __restrict__ controls,
    const float* __restrict__ robot_points,
    const float* __restrict__ x0,
    const float* __restrict__ xd0,
    const float* __restrict__ R0,
    const float* __restrict__ omega0,
    float* __restrict__ out,
    int T)
{
    const int b = blockIdx.x;
    const int tid = threadIdx.x;
    const int wv = tid >> 6;
    __shared__ f4l ldsX[2][2][2];
    __shared__ f4l ldsY[2][2];

    const float* __restrict__ zg = z_grid + (size_t)b * (GH * GW);
    const float* __restrict__ fg = friction + (size_t)b * (GH * GW);
    const float* __restrict__ ct = controls + (size_t)b * (T * 2);
    float* __restrict__ ob = out + (size_t)b * (T * 3);

    const float ppx = robot_points[tid * 3 + 0];
    const float ppy = robot_points[tid * 3 + 1];
    const float ppz = robot_points[tid * 3 + 2];
    const bool isL = (ppy < 0.0f);

    float I6[6];
    I6[0] = ppy * ppy + ppz * ppz;
    I6[1] = ppx * ppx + ppz * ppz;
    I6[2] = ppx * ppx + ppy * ppy;
    I6[3] = ppx * ppy;
    I6[4] = ppx * ppz;
    I6[5] = ppy * ppz;
    #pragma unroll
    for (int k = 0; k < 6; ++k) I6[k] = rl63(wave_sum63(I6[k]));
    if ((tid & 63) == 63) {
        f4l t0; t0.x = I6[0]; t0.y = I6[1]; t0.z = I6[2]; t0.w = I6[3];
        f4l t1; t1.x = I6[4]; t1.y = I6[5]; t1.z = 0.f; t1.w = 0.f;
        ldsY[wv][0] = t0; ldsY[wv][1] = t1;
    }
    __syncthreads();
    {
        f4l o0 = ldsY[wv ^ 1][0], o1 = ldsY[wv ^ 1][1];
        I6[0] += o0.x; I6[1] += o0.y; I6[2] += o0.z;
        I6[3] += o0.w; I6[4] += o1.x; I6[5] += o1.y;
    }
    const float mp = 0.3125f;
    {
        double a = mp * I6[0], bb = mp * I6[1], c = mp * I6[2];
        double d = -(mp * I6[3]), e = -(mp * I6[4]), f = -(mp * I6[5]);
        double C00 = bb * c - f * f, C01 = e * f - d * c, C02 = d * f - bb * e;
        double C11 = a * c - e * e, C12 = d * e - a * f, C22 = a * bb - d * d;
        double idet = 1.0 / (a * C00 + d * C01 + e * C02);
        I6[0] = (float)(C00 * idet); I6[1] = (float)(C11 * idet); I6[2] = (float)(C22 * idet);
        I6[3] = (float)(C01 * idet); I6[4] = (float)(C02 * idet); I6[5] = (float)(C12 * idet);
    }
    const float i00 = I6[0], i11 = I6[1], i22 = I6[2];
    const float i01 = I6[3], i02 = I6[4], i12 = I6[5];

    float X0 = x0[b * 3 + 0], X1 = x0[b * 3 + 1], X2 = x0[b * 3 + 2];
    float V0 = xd0[b * 3 + 0], V1 = xd0[b * 3 + 1], V2 = xd0[b * 3 + 2];
    float W0 = omega0[b * 3 + 0], W1 = omega0[b * 3 + 1], W2 = omega0[b * 3 + 2];
    float R00 = R0[b * 9 + 0], R01 = R0[b * 9 + 1], R02 = R0[b * 9 + 2];
    float R10 = R0[b * 9 + 3], R11 = R0[b * 9 + 4], R12 = R0[b * 9 + 5];
    float R20 = R0[b * 9 + 6], R21 = R0[b * 9 + 7], R22 = R0[b * 9 + 8];

    for (int t = 0; t < T; ++t) {
        const int par = t & 1;
        f2 cc = *(const f2*)(ct + t * 2);
        float rx = R00 * ppx + R01 * ppy + R02 * ppz;
        float ry = R10 * ppx + R11 * ppy + R12 * ppz;
        float rz = R20 * ppx + R21 * ppy + R22 * ppz;
        float Px = rx + X0, Py = ry + X1, Pz = rz + X2;
        float l0 = Px - X0, l1 = Py - X1, l2 = Pz - X2;
        float u = (Px + 12.8f) * 10.0f;
        u = fminf(fmaxf(u, 0.0f), 254.999f);
        float vvq = (Py + 12.8f) * 10.0f;
        vvq = fminf(fmaxf(vvq, 0.0f), 254.999f);
        int u0 = (int)u, v0 = (int)vvq;
        bool interior = (u0 >= 1) & (u0 <= 253) & (v0 >= 1) & (v0 <= 253);
        bool fastp = __all(interior);

        float zz, fr, gxs, gys;
        float du = u - (float)u0, dv = vvq - (float)v0;
        float w00 = (1.0f - du) * (1.0f - dv);
        float w10 = du * (1.0f - dv);
        float w01 = (1.0f - du) * dv;
        float w11 = du * dv;

        float cv = cc.x, cw = cc.y;
        float half = (cw * 0.6f) * 0.5f;
        float vLs = cv - half, vRs = cv + half;
        float rtn = frsq(R00 * R00 + R10 * R10 + R20 * R20);
        float th0 = R00 * rtn, th1 = R10 * rtn, th2 = R20 * rtn;
        float xp0 = V0 + (W1 * l2 - W2 * l1);
        float xp1 = V1 + (W2 * l0 - W0 * l2);
        float xp2 = V2 + (W0 * l1 - W1 * l0);
        float cmd = isL ? vLs : vRs;
        float ct0 = cmd * th0 - xp0;
        float ct1 = cmd * th1 - xp1;
        float ct2 = cmd * th2 - xp2;

        if (fastp) {
            int base = (u0 - 1) * GW + (v0 - 1);
            f4 P0 = *(const f4*)(zg + base);
            f4 P1 = *(const f4*)(zg + base + GW);
            f4 P2 = *(const f4*)(zg + base + 2 * GW);
            f4 P3 = *(const f4*)(zg + base + 3 * GW);
            int fb = u0 * GW + v0;
            f2 F0 = *(const f2*)(fg + fb);
            f2 F1 = *(const f2*)(fg + fb + GW);
            zz = P1.y * w00 + P2.y * w10 + P1.z * w01 + P2.z * w11;
            fr = F0.x * w00 + F1.x * w10 + F0.y * w01 + F1.y * w11;
            float gx00 = (P2.y - P0.y) * 5.0f;
            float gx10 = (P3.y - P1.y) * 5.0f;
            float gx01 = (P2.z - P0.z) * 5.0f;
            float gx11 = (P3.z - P1.z) * 5.0f;
            float gy00 = (P1.z - P1.x) * 5.0f;
            float gy10 = (P2.z - P2.x) * 5.0f;
            float gy01 = (P1.w - P1.y) * 5.0f;
            float gy11 = (P2.w - P2.y) * 5.0f;
            gxs = gx00 * w00 + gx10 * w10 + gx01 * w01 + gx11 * w11;
            gys = gy00 * w00 + gy10 * w10 + gy01 * w01 + gy11 * w11;
        } else {
            int basei = u0 * GW + v0;
            zz = zg[basei] * w00 + zg[basei + GW] * w10 + zg[basei + 1] * w01 + zg[basei + GW + 1] * w11;
            fr = fg[basei] * w00 + fg[basei + GW] * w10 + fg[basei + 1] * w01 + fg[basei + GW + 1] * w11;
            float gx[2][2], gy[2][2];
            #pragma unroll
            for (int ii = 0; ii < 2; ++ii) {
                int i = u0 + ii;
                int ipu = (i < GH - 1) ? i + 1 : i;
                int imu = (i > 0) ? i - 1 : i;
                float scu = (ipu - imu == 2) ? 0.5f : 1.0f;
                #pragma unroll
                for (int jj = 0; jj < 2; ++jj) {
                    int j = v0 + jj;
                    int jpv = (j < GW - 1) ? j + 1 : j;
                    int jmv = (j > 0) ? j - 1 : j;
                    float scv = (jpv - jmv == 2) ? 0.5f : 1.0f;
                    gx[ii][jj] = ((zg[ipu * GW + j] - zg[imu * GW + j]) * scu) * 10.0f;
                    gy[ii][jj] = ((zg[i * GW + jpv] - zg[i * GW + jmv]) * scv) * 10.0f;
                }
            }
            gxs = gx[0][0] * w00 + gx[1][0] * w10 + gx[0][1] * w01 + gx[1][1] * w11;
            gys = gy[0][0] * w00 + gy[1][0] * w10 + gy[0][1] * w01 + gy[1][1] * w11;
        }

        float rn = frsq(gxs * gxs + gys * gys + 1.0f);
        float nx = -gxs * rn, ny = -gys * rn, nzc = rn;
        float dh = Pz - zz;
        float ex = fexp2(dh * 14.426950408889634f);
        float ic = frcp(1.0f + ex);
        float xdn = xp0 * nx + xp1 * ny + xp2 * nzc;

        float mag = -(1000.0f * dh + 100.0f * xdn);
        float mic = mag * ic;
        float m_abs = fabsf(mic);
        float sl0 = fr * ct0, sl1 = fr * ct1, sl2 = fr * ct2;
        float sdn = sl0 * nx + sl1 * ny + sl2 * nzc;
        float st0 = sl0 - sdn * nx;
        float st1 = sl1 - sdn * ny;
        float st2 = sl2 - sdn * nzc;
        float g0 = mic * nx  + m_abs * st0;
        float g1 = mic * ny  + m_abs * st1;
        float g2 = mic * nzc + m_abs * st2;
        float q0 = l1 * g2 - l2 * g1;
        float q1 = l2 * g0 - l0 * g2;
        float q2 = l0 * g1 - l1 * g0;
        float stm = fmaxf(fmaxf(fabsf(st0), fabsf(st1)), fabsf(st2));
        float worst = fmaxf(stm, 1.0f) * m_abs;

        float d_ic = wave_sum63(ic);
        float d_g0 = wave_sum63(g0), d_g1 = wave_sum63(g1), d_g2 = wave_sum63(g2);
        float d_q0 = wave_sum63(q0), d_q1 = wave_sum63(q1), d_q2 = wave_sum63(q2);
        float d_rw = wave_max63(worst);
        if ((tid & 63) == 63) {
            f4l h0; h0.x = d_g0; h0.y = d_g1; h0.z = d_g2; h0.w = d_q0;
            f4l h1; h1.x = d_q1; h1.y = d_q2; h1.z = d_ic; h1.w = d_rw;
            ldsX[par][wv][0] = h0; ldsX[par][wv][1] = h1;
        }
        float o_ic = rl63(d_ic);
        float o_g0 = rl63(d_g0), o_g1 = rl63(d_g1), o_g2 = rl63(d_g2);
        float o_q0 = rl63(d_q0), o_q1 = rl63(d_q1), o_q2 = rl63(d_q2);
        float o_rw = rl63(d_rw);
        __syncthreads();
        f4l e0 = ldsX[par][wv ^ 1][0], e1 = ldsX[par][wv ^ 1][1];
        float sic = o_ic + e1.z;
        float rwm = fmaxf(o_rw, e1.w);
        float rsic = frcp(sic);

        float FT0, FT1, FT2, TQ0, TQ1, TQ2;
        if (rwm <= 391.0f * sic) {
            FT0 = (o_g0 + e0.x) * rsic;
            FT1 = (o_g1 + e0.y) * rsic;
            FT2 = (o_g2 + e0.z) * rsic;
            TQ0 = (o_q0 + e0.w) * rsic;
            TQ1 = (o_q1 + e1.x) * rsic;
            TQ2 = (o_q2 + e1.y) * rsic;
        } else {
            float s = mic * rsic;
            float Fr0 = fminf(fmaxf(s * nx,  -392.0f), 392.0f);
            float Fr1 = fminf(fmaxf(s * ny,  -392.0f), 392.0f);
            float Fr2 = fminf(fmaxf(s * nzc, -392.0f), 392.0f);
            float Nm = __builtin_amdgcn_sqrtf(Fr0 * Fr0 + Fr1 * Fr1 + Fr2 * Fr2);
            float Ff0 = fminf(fmaxf(Nm * st0, -392.0f), 392.0f);
            float Ff1 = fminf(fmaxf(Nm * st1, -392.0f), 392.0f);
            float Ff2 = fminf(fmaxf(Nm * st2, -392.0f), 392.0f);
            float S0 = Fr0 + Ff0, S1 = Fr1 + Ff1, S2 = Fr2 + Ff2;
            float U0 = l1 * S2 - l2 * S1;
            float U1 = l2 * S0 - l0 * S2;
            float U2 = l0 * S1 - l1 * S0;
            float dS0 = wave_sum63(S0), dS1 = wave_sum63(S1), dS2 = wave_sum63(S2);
            float dU0 = wave_sum63(U0), dU1 = wave_sum63(U1), dU2 = wave_sum63(U2);
            if ((tid & 63) == 63) {
                f4l h0; h0.x = dS0; h0.y = dS1; h0.z = dS2; h0.w = dU0;
                f4l h1; h1.x = dU1; h1.y = dU2; h1.z = 0.f; h1.w = 0.f;
                ldsY[wv][0] = h0; ldsY[wv][1] = h1;
            }
            __syncthreads();
            f4l c0 = ldsY[wv ^ 1][0], c1 = ldsY[wv ^ 1][1];
            FT0 = rl63(dS0) + c0.x; FT1 = rl63(dS1) + c0.y; FT2 = rl63(dS2) + c0.z;
            TQ0 = rl63(dU0) + c0.w; TQ1 = rl63(dU1) + c1.x; TQ2 = rl63(dU2) + c1.y;
        }

        float od0 = fminf(fmaxf(TQ0 * i00 + TQ1 * i01 + TQ2 * i02, -2.0f), 2.0f);
        float od1 = fminf(fmaxf(TQ0 * i01 + TQ1 * i11 + TQ2 * i12, -2.0f), 2.0f);
        float od2 = fminf(fmaxf(TQ0 * i02 + TQ1 * i12 + TQ2 * i22, -2.0f), 2.0f);

        V0 += (FT0 * 0.025f) * 0.01f;
        V1 += (FT1 * 0.025f) * 0.01f;
        V2 += ((-392.0f + FT2) * 0.025f) * 0.01f;
        X0 += V0 * 0.01f; X1 += V1 * 0.01f; X2 += V2 * 0.01f;
        W0 += od0 * 0.01f; W1 += od1 * 0.01f; W2 += od2 * 0.01f;

        if (tid == 0) {
            ob[t * 3 + 0] = X0;
            ob[t * 3 + 1] = X1;
            ob[t * 3 + 2] = X2;
        }

        float th2s = W0 * W0 + W1 * W1 + W2 * W2;
        float a2 = th2s * 1e-4f;
        float s1 = 0.01f - a2 * (0.01f / 6.0f);
        float c2 = 5e-5f - a2 * (1e-4f / 24.0f);
        float w01p = W0 * W1, w02p = W0 * W2, w12p = W1 * W2;
        float A00 = 1.0f - c2 * (W1 * W1 + W2 * W2);
        float A11 = 1.0f - c2 * (W0 * W0 + W2 * W2);
        float A22 = 1.0f - c2 * (W0 * W0 + W1 * W1);
        float A01 = c2 * w01p - s1 * W2;
        float A10 = c2 * w01p + s1 * W2;
        float A02 = c2 * w02p + s1 * W1;
        float A20 = c2 * w02p - s1 * W1;
        float A12 = c2 * w12p - s1 * W0;
        float A21 = c2 * w12p + s1 * W0;
        float N00 = R00 * A00 + R01 * A10 + R02 * A20;
        float N01 = R00 * A01 + R01 * A11 + R02 * A21;
        float N02 = R00 * A02 + R01 * A12 + R02 * A22;
        float N10 = R10 * A00 + R11 * A10 + R12 * A20;
        float N11 = R10 * A01 + R11 * A11 + R12 * A21;
        float N12 = R10 * A02 + R11 * A12 + R12 * A22;
        float N20 = R20 * A00 + R21 * A10 + R22 * A20;
        float N21 = R20 * A01 + R21 * A11 + R22 * A21;
        float N22 = R20 * A02 + R21 * A12 + R22 * A22;
        R00 = N00; R01 = N01; R02 = N02;
        R10 = N10; R11 = N11; R12 = N12;
        R20 = N20; R21 = N21; R22 = N22;
    }
}

extern "C" void kernel_launch(void* const* d_in, const int* in_sizes, int n_in,
                              void* d_out, int out_size, void* d_ws, size_t ws_size,
                              hipStream_t stream) {
    const float* z_grid       = (const float*)d_in[0];
    const float* friction     = (const float*)d_in[1];
    const float* controls     = (const float*)d_in[2];
    const float* robot_points = (const float*)d_in[3];
    const float* x0           = (const float*)d_in[4];
    const float* xd0          = (const float*)d_in[5];
    const float* R0           = (const float*)d_in[6];
    const float* omega0       = (const float*)d_in[7];
    int B = in_sizes[4] / 3;                 // 64
    int T = in_sizes[2] / (B * 2);           // 500
    size_t need = (size_t)B * GH * GW * sizeof(float) * 4;
    if (ws_size >= need) {
        prep_kernel<<<dim3(GH, B), GW, 0, stream>>>(z_grid, friction, (f4*)d_ws);
        int nb = (B + 1) / 2;
        dphys_kernel2p<<<nb, 128, 0, stream>>>((const f4*)d_ws, controls, robot_points,
                                               x0, xd0, R0, omega0, (float*)d_out, T, B);
    } else {
        dphys_kernel_fb<<<B, 128, 0, stream>>>(z_grid, friction, controls, robot_points,
                                               x0, xd0, R0, omega0, (float*)d_out, T);
    }
}

// Round 12
// 447.695 us; speedup vs baseline: 2.0458x; 1.6276x over previous
//
#include <hip/hip_runtime.h>
#include <math.h>

#define GH 256
#define GW 256

typedef float f4 __attribute__((ext_vector_type(4), aligned(4)));
typedef float f2 __attribute__((ext_vector_type(2), aligned(4)));
typedef float f4l __attribute__((ext_vector_type(4)));   // 16B-aligned

template<int CTRL, int RMASK>
__device__ __forceinline__ float dpp_add(float v) {
    int r = __builtin_amdgcn_update_dpp(0, __builtin_bit_cast(int, v), CTRL, RMASK, 0xF, true);
    return v + __builtin_bit_cast(float, r);
}
template<int CTRL, int RMASK>
__device__ __forceinline__ float dpp_max(float v) {
    int r = __builtin_amdgcn_update_dpp(0, __builtin_bit_cast(int, v), CTRL, RMASK, 0xF, true);
    return fmaxf(v, __builtin_bit_cast(float, r));
}
__device__ __forceinline__ float wave_sum63(float v) {
    v = dpp_add<0xB1, 0xF>(v);
    v = dpp_add<0x4E, 0xF>(v);
    v = dpp_add<0x141, 0xF>(v);
    v = dpp_add<0x140, 0xF>(v);
    v = dpp_add<0x142, 0xA>(v);
    v = dpp_add<0x143, 0xC>(v);
    return v;
}
__device__ __forceinline__ float wave_max63(float v) {
    v = dpp_max<0xB1, 0xF>(v);
    v = dpp_max<0x4E, 0xF>(v);
    v = dpp_max<0x141, 0xF>(v);
    v = dpp_max<0x140, 0xF>(v);
    v = dpp_max<0x142, 0xA>(v);
    v = dpp_max<0x143, 0xC>(v);
    return v;
}
__device__ __forceinline__ float rl63(float v) {
    return __builtin_bit_cast(float, __builtin_amdgcn_readlane(__builtin_bit_cast(int, v), 63));
}
__device__ __forceinline__ float frcp(float x)  { return __builtin_amdgcn_rcpf(x); }
__device__ __forceinline__ float frsq(float x)  { return __builtin_amdgcn_rsqf(x); }
__device__ __forceinline__ float fexp2(float x) { return __builtin_amdgcn_exp2f(x); }

// LDS-only barrier: drain LDS ops, sync waves. Avoids __syncthreads' vmcnt(0)
// drain (which would stall on the in-flight output stores / texture loads).
#define LDS_BARRIER() asm volatile("s_waitcnt lgkmcnt(0)\n\ts_barrier" ::: "memory")

// ---------- prep: per-cell {z, gx, gy, fr} with exact edge semantics ----------
__global__ __launch_bounds__(256) void prep_kernel(
    const float* __restrict__ z_grid,
    const float* __restrict__ friction,
    f4* __restrict__ tex)
{
    const int j = threadIdx.x;
    const int i = blockIdx.x;
    const int b = blockIdx.y;
    const float* __restrict__ z = z_grid + (size_t)b * (GH * GW);
    int ipu = (i < GH - 1) ? i + 1 : i;
    int imu = (i > 0) ? i - 1 : i;
    int jpv = (j < GW - 1) ? j + 1 : j;
    int jmv = (j > 0) ? j - 1 : j;
    float scu = (ipu - imu == 2) ? 0.5f : 1.0f;
    float scv = (jpv - jmv == 2) ? 0.5f : 1.0f;
    float gx = ((z[ipu * GW + j] - z[imu * GW + j]) * scu) * 10.0f;
    float gy = ((z[i * GW + jpv] - z[i * GW + jmv]) * scv) * 10.0f;
    f4 o;
    o.x = z[i * GW + j];
    o.y = gx;
    o.z = gy;
    o.w = friction[(size_t)b * (GH * GW) + i * GW + j];
    tex[(size_t)b * (GH * GW) + i * GW + j] = o;
}

// One simulated step. PH = -1: runtime-parity, store X scalar each step.
// PH in {0,1,2,3}: compile-time phase; buffer X into sb0..sb2, flush 3x
// dwordx4 at PH==3 (store-ack wait amortized over 4 steps).
#define STEP_BODY(TCUR, PH)                                                     \
do {                                                                            \
    const int par_ = (PH < 0) ? ((TCUR) & 1) : ((PH) & 1);                      \
    f2 cc = *(const f2*)(ct + (TCUR) * 2);                                      \
    /* address phase: loads in flight ASAP */                                   \
    float rx = R00 * ppx + R01 * ppy + R02 * ppz;                               \
    float ry = R10 * ppx + R11 * ppy + R12 * ppz;                               \
    float rz = R20 * ppx + R21 * ppy + R22 * ppz;                               \
    float Px = rx + X0, Py = ry + X1, Pz = rz + X2;                             \
    float l0 = Px - X0, l1 = Py - X1, l2 = Pz - X2;                             \
    float u = fminf(fmaxf((Px + 12.8f) * 10.0f, 0.0f), 254.999f);               \
    float vvq = fminf(fmaxf((Py + 12.8f) * 10.0f, 0.0f), 254.999f);             \
    int u0 = (int)u, v0 = (int)vvq;                                             \
    int idx = (u0 << 8) + v0;                                                   \
    f4 c00 = tb[idx];                                                           \
    f4 c01 = tb[idx + 1];                                                       \
    f4 c10 = tb[idx + GW];                                                      \
    f4 c11 = tb[idx + GW + 1];                                                  \
    /* load-shadow work */                                                      \
    float du = u - (float)u0, dv = vvq - (float)v0;                             \
    float w00 = (1.0f - du) * (1.0f - dv);                                      \
    float w10 = du * (1.0f - dv);                                               \
    float w01 = (1.0f - du) * dv;                                               \
    float w11 = du * dv;                                                        \
    float cv = cc.x, cw = cc.y;                                                 \
    float half_ = (cw * 0.6f) * 0.5f;                                           \
    float vLs = cv - half_, vRs = cv + half_;                                   \
    /* thrust = R column 0 (norm = 1 +- ~1e-5 over 500 steps; rsq dropped) */   \
    float xp0 = V0 + (W1 * l2 - W2 * l1);                                       \
    float xp1 = V1 + (W2 * l0 - W0 * l2);                                       \
    float xp2 = V2 + (W0 * l1 - W1 * l0);                                       \
    float cmd = isL ? vLs : vRs;                                                \
    float ct0 = cmd * R00 - xp0;                                                \
    float ct1 = cmd * R10 - xp1;                                                \
    float ct2 = cmd * R20 - xp2;                                                \
    /* bilinear blend of {z, gx, gy, fr} */                                     \
    f4 cb = c00 * w00 + c10 * w10 + c01 * w01 + c11 * w11;                      \
    float zz = cb.x, gxs = cb.y, gys = cb.z, fr = cb.w;                         \
    float rn = frsq(gxs * gxs + gys * gys + 1.0f);                              \
    float nx = -gxs * rn, ny = -gys * rn, nzc = rn;                             \
    float dh = Pz - zz;                                                         \
    float ex = fexp2(dh * 14.426950408889634f);                                 \
    float ic = frcp(1.0f + ex);                                                 \
    float xdn = xp0 * nx + xp1 * ny + xp2 * nzc;                                \
    float mag = -(1000.0f * dh + 100.0f * xdn);                                 \
    float mic = mag * ic;                                                       \
    float m_abs = fabsf(mic);                                                   \
    float sl0 = fr * ct0, sl1 = fr * ct1, sl2 = fr * ct2;                       \
    float sdn = sl0 * nx + sl1 * ny + sl2 * nzc;                                \
    float st0 = sl0 - sdn * nx;                                                 \
    float st1 = sl1 - sdn * ny;                                                 \
    float st2 = sl2 - sdn * nzc;                                                \
    float g0 = mic * nx  + m_abs * st0;                                         \
    float g1 = mic * ny  + m_abs * st1;                                         \
    float g2 = mic * nzc + m_abs * st2;                                         \
    float q0 = l1 * g2 - l2 * g1;                                               \
    float q1 = l2 * g0 - l0 * g2;                                               \
    float q2 = l0 * g1 - l1 * g0;                                               \
    float stm = fmaxf(fmaxf(fabsf(st0), fabsf(st1)), fabsf(st2));               \
    float worst = fmaxf(stm, 1.0f) * m_abs;                                     \
    /* 8 pipelined DPP chains; own via readlane, other via LDS */               \
    float d_ic = wave_sum63(ic);                                                \
    float d_g0 = wave_sum63(g0), d_g1 = wave_sum63(g1), d_g2 = wave_sum63(g2);  \
    float d_q0 = wave_sum63(q0), d_q1 = wave_sum63(q1), d_q2 = wave_sum63(q2);  \
    float d_rw = wave_max63(worst);                                             \
    if ((tid & 63) == 63) {                                                     \
        f4l h0; h0.x = d_g0; h0.y = d_g1; h0.z = d_g2; h0.w = d_q0;             \
        f4l h1; h1.x = d_q1; h1.y = d_q2; h1.z = d_ic; h1.w = d_rw;             \
        ldsX[par_][wv][0] = h0; ldsX[par_][wv][1] = h1;                         \
    }                                                                           \
    float o_ic = rl63(d_ic);                                                    \
    float o_g0 = rl63(d_g0), o_g1 = rl63(d_g1), o_g2 = rl63(d_g2);              \
    float o_q0 = rl63(d_q0), o_q1 = rl63(d_q1), o_q2 = rl63(d_q2);              \
    float o_rw = rl63(d_rw);                                                    \
    LDS_BARRIER();                                                              \
    f4l e0 = ldsX[par_][wv ^ 1][0], e1 = ldsX[par_][wv ^ 1][1];                 \
    float sic = o_ic + e1.z;                                                    \
    float rwm = fmaxf(o_rw, e1.w);                                              \
    float rsic = frcp(sic);                                                     \
    float FT0, FT1, FT2, TQ0, TQ1, TQ2;                                         \
    if (rwm <= 391.0f * sic) {                                                  \
        FT0 = (o_g0 + e0.x) * rsic;                                             \
        FT1 = (o_g1 + e0.y) * rsic;                                             \
        FT2 = (o_g2 + e0.z) * rsic;                                             \
        TQ0 = (o_q0 + e0.w) * rsic;                                             \
        TQ1 = (o_q1 + e1.x) * rsic;                                             \
        TQ2 = (o_q2 + e1.y) * rsic;                                             \
    } else {                                                                    \
        float s = mic * rsic;                                                   \
        float Fr0 = fminf(fmaxf(s * nx,  -392.0f), 392.0f);                     \
        float Fr1 = fminf(fmaxf(s * ny,  -392.0f), 392.0f);                     \
        float Fr2 = fminf(fmaxf(s * nzc, -392.0f), 392.0f);                     \
        float Nm = __builtin_amdgcn_sqrtf(Fr0 * Fr0 + Fr1 * Fr1 + Fr2 * Fr2);   \
        float Ff0 = fminf(fmaxf(Nm * st0, -392.0f), 392.0f);                    \
        float Ff1 = fminf(fmaxf(Nm * st1, -392.0f), 392.0f);                    \
        float Ff2 = fminf(fmaxf(Nm * st2, -392.0f), 392.0f);                    \
        float S0 = Fr0 + Ff0, S1 = Fr1 + Ff1, S2 = Fr2 + Ff2;                   \
        float U0 = l1 * S2 - l2 * S1;                                           \
        float U1 = l2 * S0 - l0 * S2;                                           \
        float U2 = l0 * S1 - l1 * S0;                                           \
        float dS0 = wave_sum63(S0), dS1 = wave_sum63(S1), dS2 = wave_sum63(S2); \
        float dU0 = wave_sum63(U0), dU1 = wave_sum63(U1), dU2 = wave_sum63(U2); \
        if ((tid & 63) == 63) {                                                 \
            f4l h0; h0.x = dS0; h0.y = dS1; h0.z = dS2; h0.w = dU0;             \
            f4l h1; h1.x = dU1; h1.y = dU2; h1.z = 0.f; h1.w = 0.f;             \
            ldsY[wv][0] = h0; ldsY[wv][1] = h1;                                 \
        }                                                                       \
        LDS_BARRIER();                                                          \
        f4l c0 = ldsY[wv ^ 1][0], c1 = ldsY[wv ^ 1][1];                         \
        FT0 = rl63(dS0) + c0.x; FT1 = rl63(dS1) + c0.y; FT2 = rl63(dS2) + c0.z; \
        TQ0 = rl63(dU0) + c0.w; TQ1 = rl63(dU1) + c1.x; TQ2 = rl63(dU2) + c1.y; \
    }                                                                           \
    float od0 = fminf(fmaxf(TQ0 * i00 + TQ1 * i01 + TQ2 * i02, -2.0f), 2.0f);   \
    float od1 = fminf(fmaxf(TQ0 * i01 + TQ1 * i11 + TQ2 * i12, -2.0f), 2.0f);   \
    float od2 = fminf(fmaxf(TQ0 * i02 + TQ1 * i12 + TQ2 * i22, -2.0f), 2.0f);   \
    V0 += (FT0 * 0.025f) * 0.01f;                                               \
    V1 += (FT1 * 0.025f) * 0.01f;                                               \
    V2 += ((-392.0f + FT2) * 0.025f) * 0.01f;                                   \
    X0 += V0 * 0.01f; X1 += V1 * 0.01f; X2 += V2 * 0.01f;                       \
    W0 += od0 * 0.01f; W1 += od1 * 0.01f; W2 += od2 * 0.01f;                    \
    if (PH < 0) {                                                               \
        if (tid == 0) {                                                         \
            ob[(TCUR) * 3 + 0] = X0;                                            \
            ob[(TCUR) * 3 + 1] = X1;                                            \
            ob[(TCUR) * 3 + 2] = X2;                                            \
        }                                                                       \
    } else if (PH == 0) { sb0.x = X0; sb0.y = X1; sb0.z = X2; }                 \
    else if (PH == 1) { sb0.w = X0; sb1.x = X1; sb1.y = X2; }                   \
    else if (PH == 2) { sb1.z = X0; sb1.w = X1; sb2.x = X2; }                   \
    else {                                                                      \
        sb2.y = X0; sb2.z = X1; sb2.w = X2;                                     \
        if (tid == 0) {                                                         \
            f4* op = (f4*)(ob + ((TCUR) - 3) * 3);                              \
            op[0] = sb0; op[1] = sb1; op[2] = sb2;                              \
        }                                                                       \
    }                                                                           \
    /* polynomial Rodrigues (R7-validated) */                                   \
    float th2s = W0 * W0 + W1 * W1 + W2 * W2;                                   \
    float a2 = th2s * 1e-4f;                                                    \
    float s1 = 0.01f - a2 * (0.01f / 6.0f);                                     \
    float c2 = 5e-5f - a2 * (1e-4f / 24.0f);                                    \
    float w01p = W0 * W1, w02p = W0 * W2, w12p = W1 * W2;                       \
    float A00 = 1.0f - c2 * (W1 * W1 + W2 * W2);                                \
    float A11 = 1.0f - c2 * (W0 * W0 + W2 * W2);                                \
    float A22 = 1.0f - c2 * (W0 * W0 + W1 * W1);                                \
    float A01 = c2 * w01p - s1 * W2;                                            \
    float A10 = c2 * w01p + s1 * W2;                                            \
    float A02 = c2 * w02p + s1 * W1;                                            \
    float A20 = c2 * w02p - s1 * W1;                                            \
    float A12 = c2 * w12p - s1 * W0;                                            \
    float A21 = c2 * w12p + s1 * W0;                                            \
    float N00 = R00 * A00 + R01 * A10 + R02 * A20;                              \
    float N01 = R00 * A01 + R01 * A11 + R02 * A21;                              \
    float N02 = R00 * A02 + R01 * A12 + R02 * A22;                              \
    float N10 = R10 * A00 + R11 * A10 + R12 * A20;                              \
    float N11 = R10 * A01 + R11 * A11 + R12 * A21;                              \
    float N12 = R10 * A02 + R11 * A12 + R12 * A22;                              \
    float N20 = R20 * A00 + R21 * A10 + R22 * A20;                              \
    float N21 = R20 * A01 + R21 * A11 + R22 * A21;                              \
    float N22 = R20 * A02 + R21 * A12 + R22 * A22;                              \
    R00 = N00; R01 = N01; R02 = N02;                                            \
    R10 = N10; R11 = N11; R12 = N12;                                            \
    R20 = N20; R21 = N21; R22 = N22;                                            \
} while (0)

// ---------- main sim kernel (texture path) ----------
__global__ __launch_bounds__(128) void dphys_kernel(
    const f4* __restrict__ tex,
    const float* __restrict__ controls,
    const float* __restrict__ robot_points,
    const float* __restrict__ x0,
    const float* __restrict__ xd0,
    const float* __restrict__ R0,
    const float* __restrict__ omega0,
    float* __restrict__ out,
    int T)
{
    const int b = blockIdx.x;
    const int tid = threadIdx.x;
    const int wv = tid >> 6;
    __shared__ f4l ldsX[2][2][2];
    __shared__ f4l ldsY[2][2];

    const f4* __restrict__ tb = tex + (size_t)b * (GH * GW);
    const float* __restrict__ ct = controls + (size_t)b * (T * 2);
    float* __restrict__ ob = out + (size_t)b * (T * 3);

    const float ppx = robot_points[tid * 3 + 0];
    const float ppy = robot_points[tid * 3 + 1];
    const float ppz = robot_points[tid * 3 + 2];
    const bool isL = (ppy < 0.0f);

    // inertia (one-time)
    float I6[6];
    I6[0] = ppy * ppy + ppz * ppz;
    I6[1] = ppx * ppx + ppz * ppz;
    I6[2] = ppx * ppx + ppy * ppy;
    I6[3] = ppx * ppy;
    I6[4] = ppx * ppz;
    I6[5] = ppy * ppz;
    #pragma unroll
    for (int k = 0; k < 6; ++k) I6[k] = rl63(wave_sum63(I6[k]));
    if ((tid & 63) == 63) {
        f4l t0; t0.x = I6[0]; t0.y = I6[1]; t0.z = I6[2]; t0.w = I6[3];
        f4l t1; t1.x = I6[4]; t1.y = I6[5]; t1.z = 0.f; t1.w = 0.f;
        ldsY[wv][0] = t0; ldsY[wv][1] = t1;
    }
    __syncthreads();
    {
        f4l o0 = ldsY[wv ^ 1][0], o1 = ldsY[wv ^ 1][1];
        I6[0] += o0.x; I6[1] += o0.y; I6[2] += o0.z;
        I6[3] += o0.w; I6[4] += o1.x; I6[5] += o1.y;
    }
    const float mp = 0.3125f;
    {
        double a = mp * I6[0], bb = mp * I6[1], c = mp * I6[2];
        double d = -(mp * I6[3]), e = -(mp * I6[4]), f = -(mp * I6[5]);
        double C00 = bb * c - f * f, C01 = e * f - d * c, C02 = d * f - bb * e;
        double C11 = a * c - e * e, C12 = d * e - a * f, C22 = a * bb - d * d;
        double idet = 1.0 / (a * C00 + d * C01 + e * C02);
        I6[0] = (float)(C00 * idet); I6[1] = (float)(C11 * idet); I6[2] = (float)(C22 * idet);
        I6[3] = (float)(C01 * idet); I6[4] = (float)(C02 * idet); I6[5] = (float)(C12 * idet);
    }
    const float i00 = I6[0], i11 = I6[1], i22 = I6[2];
    const float i01 = I6[3], i02 = I6[4], i12 = I6[5];

    float X0 = x0[b * 3 + 0], X1 = x0[b * 3 + 1], X2 = x0[b * 3 + 2];
    float V0 = xd0[b * 3 + 0], V1 = xd0[b * 3 + 1], V2 = xd0[b * 3 + 2];
    float W0 = omega0[b * 3 + 0], W1 = omega0[b * 3 + 1], W2 = omega0[b * 3 + 2];
    float R00 = R0[b * 9 + 0], R01 = R0[b * 9 + 1], R02 = R0[b * 9 + 2];
    float R10 = R0[b * 9 + 3], R11 = R0[b * 9 + 4], R12 = R0[b * 9 + 5];
    float R20 = R0[b * 9 + 6], R21 = R0[b * 9 + 7], R22 = R0[b * 9 + 8];

    f4 sb0, sb1, sb2;   // 4-step output buffer (phased compile-time writes)

    int t = 0;
    for (; t + 3 < T; t += 4) {
        STEP_BODY(t + 0, 0);
        STEP_BODY(t + 1, 1);
        STEP_BODY(t + 2, 2);
        STEP_BODY(t + 3, 3);
    }
    for (; t < T; ++t) {
        STEP_BODY(t, -1);
    }
}

// ---------- fallback (no-workspace path; R7/R8 structure, unchanged) ----------
__global__ __launch_bounds__(128) void dphys_kernel_fb(
    const float* __restrict__ z_grid,
    const float* __restrict__ friction,
    const float* __restrict__ controls,
    const float* __restrict__ robot_points,
    const float* __restrict__ x0,
    const float* __restrict__ xd0,
    const float* __restrict__ R0,
    const float* __restrict__ omega0,
    float* __restrict__ out,
    int T)
{
    const int b = blockIdx.x;
    const int tid = threadIdx.x;
    const int wv = tid >> 6;
    __shared__ f4l ldsX[2][2][2];
    __shared__ f4l ldsY[2][2];

    const float* __restrict__ zg = z_grid + (size_t)b * (GH * GW);
    const float* __restrict__ fg = friction + (size_t)b * (GH * GW);
    const float* __restrict__ ct = controls + (size_t)b * (T * 2);
    float* __restrict__ ob = out + (size_t)b * (T * 3);

    const float ppx = robot_points[tid * 3 + 0];
    const float ppy = robot_points[tid * 3 + 1];
    const float ppz = robot_points[tid * 3 + 2];
    const bool isL = (ppy < 0.0f);

    float I6[6];
    I6[0] = ppy * ppy + ppz * ppz;
    I6[1] = ppx * ppx + ppz * ppz;
    I6[2] = ppx * ppx + ppy * ppy;
    I6[3] = ppx * ppy;
    I6[4] = ppx * ppz;
    I6[5] = ppy * ppz;
    #pragma unroll
    for (int k = 0; k < 6; ++k) I6[k] = rl63(wave_sum63(I6[k]));
    if ((tid & 63) == 63) {
        f4l t0; t0.x = I6[0]; t0.y = I6[1]; t0.z = I6[2]; t0.w = I6[3];
        f4l t1; t1.x = I6[4]; t1.y = I6[5]; t1.z = 0.f; t1.w = 0.f;
        ldsY[wv][0] = t0; ldsY[wv][1] = t1;
    }
    __syncthreads();
    {
        f4l o0 = ldsY[wv ^ 1][0], o1 = ldsY[wv ^ 1][1];
        I6[0] += o0.x; I6[1] += o0.y; I6[2] += o0.z;
        I6[3] += o0.w; I6[4] += o1.x; I6[5] += o1.y;
    }
    const float mp = 0.3125f;
    {
        double a = mp * I6[0], bb = mp * I6[1], c = mp * I6[2];
        double d = -(mp * I6[3]), e = -(mp * I6[4]), f = -(mp * I6[5]);
        double C00 = bb * c - f * f, C01 = e * f - d * c, C02 = d * f - bb * e;
        double C11 = a * c - e * e, C12 = d * e - a * f, C22 = a * bb - d * d;
        double idet = 1.0 / (a * C00 + d * C01 + e * C02);
        I6[0] = (float)(C00 * idet); I6[1] = (float)(C11 * idet); I6[2] = (float)(C22 * idet);
        I6[3] = (float)(C01 * idet); I6[4] = (float)(C02 * idet); I6[5] = (float)(C12 * idet);
    }
    const float i00 = I6[0], i11 = I6[1], i22 = I6[2];
    const float i01 = I6[3], i02 = I6[4], i12 = I6[5];

    float X0 = x0[b * 3 + 0], X1 = x0[b * 3 + 1], X2 = x0[b * 3 + 2];
    float V0 = xd0[b * 3 + 0], V1 = xd0[b * 3 + 1], V2 = xd0[b * 3 + 2];
    float W0 = omega0[b * 3 + 0], W1 = omega0[b * 3 + 1], W2 = omega0[b * 3 + 2];
    float R00 = R0[b * 9 + 0], R01 = R0[b * 9 + 1], R02 = R0[b * 9 + 2];
    float R10 = R0[b * 9 + 3], R11 = R0[b * 9 + 4], R12 = R0[b * 9 + 5];
    float R20 = R0[b * 9 + 6], R21 = R0[b * 9 + 7], R22 = R0[b * 9 + 8];

    for (int t = 0; t < T; ++t) {
        const int par = t & 1;
        f2 cc = *(const f2*)(ct + t * 2);
        float rx = R00 * ppx + R01 * ppy + R02 * ppz;
        float ry = R10 * ppx + R11 * ppy + R12 * ppz;
        float rz = R20 * ppx + R21 * ppy + R22 * ppz;
        float Px = rx + X0, Py = ry + X1, Pz = rz + X2;
        float l0 = Px - X0, l1 = Py - X1, l2 = Pz - X2;
        float u = fminf(fmaxf((Px + 12.8f) * 10.0f, 0.0f), 254.999f);
        float vvq = fminf(fmaxf((Py + 12.8f) * 10.0f, 0.0f), 254.999f);
        int u0 = (int)u, v0 = (int)vvq;
        bool interior = (u0 >= 1) & (u0 <= 253) & (v0 >= 1) & (v0 <= 253);
        bool fastp = __all(interior);

        float zz, fr, gxs, gys;
        float du = u - (float)u0, dv = vvq - (float)v0;
        float w00 = (1.0f - du) * (1.0f - dv);
        float w10 = du * (1.0f - dv);
        float w01 = (1.0f - du) * dv;
        float w11 = du * dv;

        float cv = cc.x, cw = cc.y;
        float half = (cw * 0.6f) * 0.5f;
        float vLs = cv - half, vRs = cv + half;
        float rtn = frsq(R00 * R00 + R10 * R10 + R20 * R20);
        float th0 = R00 * rtn, th1 = R10 * rtn, th2 = R20 * rtn;
        float xp0 = V0 + (W1 * l2 - W2 * l1);
        float xp1 = V1 + (W2 * l0 - W0 * l2);
        float xp2 = V2 + (W0 * l1 - W1 * l0);
        float cmd = isL ? vLs : vRs;
        float ct0 = cmd * th0 - xp0;
        float ct1 = cmd * th1 - xp1;
        float ct2 = cmd * th2 - xp2;

        if (fastp) {
            int base = (u0 - 1) * GW + (v0 - 1);
            f4 P0 = *(const f4*)(zg + base);
            f4 P1 = *(const f4*)(zg + base + GW);
            f4 P2 = *(const f4*)(zg + base + 2 * GW);
            f4 P3 = *(const f4*)(zg + base + 3 * GW);
            int fb = u0 * GW + v0;
            f2 F0 = *(const f2*)(fg + fb);
            f2 F1 = *(const f2*)(fg + fb + GW);
            zz = P1.y * w00 + P2.y * w10 + P1.z * w01 + P2.z * w11;
            fr = F0.x * w00 + F1.x * w10 + F0.y * w01 + F1.y * w11;
            float gx00 = (P2.y - P0.y) * 5.0f;
            float gx10 = (P3.y - P1.y) * 5.0f;
            float gx01 = (P2.z - P0.z) * 5.0f;
            float gx11 = (P3.w - P1.w) * 5.0f;
            gx11 = (P3.z - P1.z) * 5.0f;
            float gy00 = (P1.z - P1.x) * 5.0f;
            float gy10 = (P2.z - P2.x) * 5.0f;
            float gy01 = (P1.w - P1.y) * 5.0f;
            float gy11 = (P2.w - P2.y) * 5.0f;
            gxs = gx00 * w00 + gx10 * w10 + gx01 * w01 + gx11 * w11;
            gys = gy00 * w00 + gy10 * w10 + gy01 * w01 + gy11 * w11;
        } else {
            int basei = u0 * GW + v0;
            zz = zg[basei] * w00 + zg[basei + GW] * w10 + zg[basei + 1] * w01 + zg[basei + GW + 1] * w11;
            fr = fg[basei] * w00 + fg[basei + GW] * w10 + fg[basei + 1] * w01 + fg[basei + GW + 1] * w11;
            float gx[2][2], gy[2][2];
            #pragma unroll
            for (int ii = 0; ii < 2; ++ii) {
                int i = u0 + ii;
                int ipu = (i < GH - 1) ? i + 1 : i;
                int imu = (i > 0) ? i - 1 : i;
                float scu = (ipu - imu == 2) ? 0.5f : 1.0f;
                #pragma unroll
                for (int jj = 0; jj < 2; ++jj) {
                    int j = v0 + jj;
                    int jpv = (j < GW - 1) ? j + 1 : j;
                    int jmv = (j > 0) ? j - 1 : j;
                    float scv = (jpv - jmv == 2) ? 0.5f : 1.0f;
                    gx[ii][jj] = ((zg[ipu * GW + j] - zg[imu * GW + j]) * scu) * 10.0f;
                    gy[ii][jj] = ((zg[i * GW + jpv] - zg[i * GW + jmv]) * scv) * 10.0f;
                }
            }
            gxs = gx[0][0] * w00 + gx[1][0] * w10 + gx[0][1] * w01 + gx[1][1] * w11;
            gys = gy[0][0] * w00 + gy[1][0] * w10 + gy[0][1] * w01 + gy[1][1] * w11;
        }

        float rn = frsq(gxs * gxs + gys * gys + 1.0f);
        float nx = -gxs * rn, ny = -gys * rn, nzc = rn;
        float dh = Pz - zz;
        float ex = fexp2(dh * 14.426950408889634f);
        float ic = frcp(1.0f + ex);
        float xdn = xp0 * nx + xp1 * ny + xp2 * nzc;

        float mag = -(1000.0f * dh + 100.0f * xdn);
        float mic = mag * ic;
        float m_abs = fabsf(mic);
        float sl0 = fr * ct0, sl1 = fr * ct1, sl2 = fr * ct2;
        float sdn = sl0 * nx + sl1 * ny + sl2 * nzc;
        float st0 = sl0 - sdn * nx;
        float st1 = sl1 - sdn * ny;
        float st2 = sl2 - sdn * nzc;
        float g0 = mic * nx  + m_abs * st0;
        float g1 = mic * ny  + m_abs * st1;
        float g2 = mic * nzc + m_abs * st2;
        float q0 = l1 * g2 - l2 * g1;
        float q1 = l2 * g0 - l0 * g2;
        float q2 = l0 * g1 - l1 * g0;
        float stm = fmaxf(fmaxf(fabsf(st0), fabsf(st1)), fabsf(st2));
        float worst = fmaxf(stm, 1.0f) * m_abs;

        float d_ic = wave_sum63(ic);
        float d_g0 = wave_sum63(g0), d_g1 = wave_sum63(g1), d_g2 = wave_sum63(g2);
        float d_q0 = wave_sum63(q0), d_q1 = wave_sum63(q1), d_q2 = wave_sum63(q2);
        float d_rw = wave_max63(worst);
        if ((tid & 63) == 63) {
            f4l h0; h0.x = d_g0; h0.y = d_g1; h0.z = d_g2; h0.w = d_q0;
            f4l h1; h1.x = d_q1; h1.y = d_q2; h1.z = d_ic; h1.w = d_rw;
            ldsX[par][wv][0] = h0; ldsX[par][wv][1] = h1;
        }
        float o_ic = rl63(d_ic);
        float o_g0 = rl63(d_g0), o_g1 = rl63(d_g1), o_g2 = rl63(d_g2);
        float o_q0 = rl63(d_q0), o_q1 = rl63(d_q1), o_q2 = rl63(d_q2);
        float o_rw = rl63(d_rw);
        __syncthreads();
        f4l e0 = ldsX[par][wv ^ 1][0], e1 = ldsX[par][wv ^ 1][1];
        float sic = o_ic + e1.z;
        float rwm = fmaxf(o_rw, e1.w);
        float rsic = frcp(sic);

        float FT0, FT1, FT2, TQ0, TQ1, TQ2;
        if (rwm <= 391.0f * sic) {
            FT0 = (o_g0 + e0.x) * rsic;
            FT1 = (o_g1 + e0.y) * rsic;
            FT2 = (o_g2 + e0.z) * rsic;
            TQ0 = (o_q0 + e0.w) * rsic;
            TQ1 = (o_q1 + e1.x) * rsic;
            TQ2 = (o_q2 + e1.y) * rsic;
        } else {
            float s = mic * rsic;
            float Fr0 = fminf(fmaxf(s * nx,  -392.0f), 392.0f);
            float Fr1 = fminf(fmaxf(s * ny,  -392.0f), 392.0f);
            float Fr2 = fminf(fmaxf(s * nzc, -392.0f), 392.0f);
            float Nm = __builtin_amdgcn_sqrtf(Fr0 * Fr0 + Fr1 * Fr1 + Fr2 * Fr2);
            float Ff0 = fminf(fmaxf(Nm * st0, -392.0f), 392.0f);
            float Ff1 = fminf(fmaxf(Nm * st1, -392.0f), 392.0f);
            float Ff2 = fminf(fmaxf(Nm * st2, -392.0f), 392.0f);
            float S0 = Fr0 + Ff0, S1 = Fr1 + Ff1, S2 = Fr2 + Ff2;
            float U0 = l1 * S2 - l2 * S1;
            float U1 = l2 * S0 - l0 * S2;
            float U2 = l0 * S1 - l1 * S0;
            float dS0 = wave_sum63(S0), dS1 = wave_sum63(S1), dS2 = wave_sum63(S2);
            float dU0 = wave_sum63(U0), dU1 = wave_sum63(U1), dU2 = wave_sum63(U2);
            if ((tid & 63) == 63) {
                f4l h0; h0.x = dS0; h0.y = dS1; h0.z = dS2; h0.w = dU0;
                f4l h1; h1.x = dU1; h1.y = dU2; h1.z = 0.f; h1.w = 0.f;
                ldsY[wv][0] = h0; ldsY[wv][1] = h1;
            }
            __syncthreads();
            f4l c0 = ldsY[wv ^ 1][0], c1 = ldsY[wv ^ 1][1];
            FT0 = rl63(dS0) + c0.x; FT1 = rl63(dS1) + c0.y; FT2 = rl63(dS2) + c0.z;
            TQ0 = rl63(dU0) + c0.w; TQ1 = rl63(dU1) + c1.x; TQ2 = rl63(dU2) + c1.y;
        }

        float od0 = fminf(fmaxf(TQ0 * i00 + TQ1 * i01 + TQ2 * i02, -2.0f), 2.0f);
        float od1 = fminf(fmaxf(TQ0 * i01 + TQ1 * i11 + TQ2 * i12, -2.0f), 2.0f);
        float od2 = fminf(fmaxf(TQ0 * i02 + TQ1 * i12 + TQ2 * i22, -2.0f), 2.0f);

        V0 += (FT0 * 0.025f) * 0.01f;
        V1 += (FT1 * 0.025f) * 0.01f;
        V2 += ((-392.0f + FT2) * 0.025f) * 0.01f;
        X0 += V0 * 0.01f; X1 += V1 * 0.01f; X2 += V2 * 0.01f;
        W0 += od0 * 0.01f; W1 += od1 * 0.01f; W2 += od2 * 0.01f;

        if (tid == 0) {
            ob[t * 3 + 0] = X0;
            ob[t * 3 + 1] = X1;
            ob[t * 3 + 2] = X2;
        }

        float th2s = W0 * W0 + W1 * W1 + W2 * W2;
        float a2 = th2s * 1e-4f;
        float s1 = 0.01f - a2 * (0.01f / 6.0f);
        float c2 = 5e-5f - a2 * (1e-4f / 24.0f);
        float w01p = W0 * W1, w02p = W0 * W2, w12p = W1 * W2;
        float A00 = 1.0f - c2 * (W1 * W1 + W2 * W2);
        float A11 = 1.0f - c2 * (W0 * W0 + W2 * W2);
        float A22 = 1.0f - c2 * (W0 * W0 + W1 * W1);
        float A01 = c2 * w01p - s1 * W2;
        float A10 = c2 * w01p + s1 * W2;
        float A02 = c2 * w02p + s1 * W1;
        float A20 = c2 * w02p - s1 * W1;
        float A12 = c2 * w12p - s1 * W0;
        float A21 = c2 * w12p + s1 * W0;
        float N00 = R00 * A00 + R01 * A10 + R02 * A20;
        float N01 = R00 * A01 + R01 * A11 + R02 * A21;
        float N02 = R00 * A02 + R01 * A12 + R02 * A22;
        float N10 = R10 * A00 + R11 * A10 + R12 * A20;
        float N11 = R10 * A01 + R11 * A11 + R12 * A21;
        float N12 = R10 * A02 + R11 * A12 + R12 * A22;
        float N20 = R20 * A00 + R21 * A10 + R22 * A20;
        float N21 = R20 * A01 + R21 * A11 + R22 * A21;
        float N22 = R20 * A02 + R21 * A12 + R22 * A22;
        R00 = N00; R01 = N01; R02 = N02;
        R10 = N10; R11 = N11; R12 = N12;
        R20 = N20; R21 = N21; R22 = N22;
    }
}

extern "C" void kernel_launch(void* const* d_in, const int* in_sizes, int n_in,
                              void* d_out, int out_size, void* d_ws, size_t ws_size,
                              hipStream_t stream) {
    const float* z_grid       = (const float*)d_in[0];
    const float* friction     = (const float*)d_in[1];
    const float* controls     = (const float*)d_in[2];
    const float* robot_points = (const float*)d_in[3];
    const float* x0           = (const float*)d_in[4];
    const float* xd0          = (const float*)d_in[5];
    const float* R0           = (const float*)d_in[6];
    const float* omega0       = (const float*)d_in[7];
    int B = in_sizes[4] / 3;                 // 64
    int T = in_sizes[2] / (B * 2);           // 500
    size_t need = (size_t)B * GH * GW * sizeof(float) * 4;
    if (ws_size >= need) {
        prep_kernel<<<dim3(GH, B), GW, 0, stream>>>(z_grid, friction, (f4*)d_ws);
        dphys_kernel<<<B, 128, 0, stream>>>((const f4*)d_ws, controls, robot_points,
                                            x0, xd0, R0, omega0, (float*)d_out, T);
    } else {
        dphys_kernel_fb<<<B, 128, 0, stream>>>(z_grid, friction, controls, robot_points,
                                               x0, xd0, R0, omega0, (float*)d_out, T);
    }
}

// Round 13
// 447.545 us; speedup vs baseline: 2.0465x; 1.0003x over previous
//
#include <hip/hip_runtime.h>
#include <math.h>

#define GH 256
#define GW 256

typedef float f4 __attribute__((ext_vector_type(4), aligned(4)));
typedef float f2 __attribute__((ext_vector_type(2), aligned(4)));
typedef float f4l __attribute__((ext_vector_type(4)));   // 16B-aligned

template<int CTRL, int RMASK>
__device__ __forceinline__ float dpp_add(float v) {
    int r = __builtin_amdgcn_update_dpp(0, __builtin_bit_cast(int, v), CTRL, RMASK, 0xF, true);
    return v + __builtin_bit_cast(float, r);
}
template<int CTRL, int RMASK>
__device__ __forceinline__ float dpp_max(float v) {
    int r = __builtin_amdgcn_update_dpp(0, __builtin_bit_cast(int, v), CTRL, RMASK, 0xF, true);
    return fmaxf(v, __builtin_bit_cast(float, r));
}
__device__ __forceinline__ float wave_sum63(float v) {
    v = dpp_add<0xB1, 0xF>(v);
    v = dpp_add<0x4E, 0xF>(v);
    v = dpp_add<0x141, 0xF>(v);
    v = dpp_add<0x140, 0xF>(v);
    v = dpp_add<0x142, 0xA>(v);
    v = dpp_add<0x143, 0xC>(v);
    return v;
}
__device__ __forceinline__ float wave_max63(float v) {
    v = dpp_max<0xB1, 0xF>(v);
    v = dpp_max<0x4E, 0xF>(v);
    v = dpp_max<0x141, 0xF>(v);
    v = dpp_max<0x140, 0xF>(v);
    v = dpp_max<0x142, 0xA>(v);
    v = dpp_max<0x143, 0xC>(v);
    return v;
}
__device__ __forceinline__ float rl63(float v) {
    return __builtin_bit_cast(float, __builtin_amdgcn_readlane(__builtin_bit_cast(int, v), 63));
}
__device__ __forceinline__ float frcp(float x)  { return __builtin_amdgcn_rcpf(x); }
__device__ __forceinline__ float frsq(float x)  { return __builtin_amdgcn_rsqf(x); }
__device__ __forceinline__ float fexp2(float x) { return __builtin_amdgcn_exp2f(x); }

// LDS-only barrier: drain LDS ops, sync waves (avoids __syncthreads' vmcnt(0) drain).
#define LDS_BARRIER() asm volatile("s_waitcnt lgkmcnt(0)\n\ts_barrier" ::: "memory")

// ---------- prep: per-cell {z, gx, gy, fr} with exact edge semantics ----------
__global__ __launch_bounds__(256) void prep_kernel(
    const float* __restrict__ z_grid,
    const float* __restrict__ friction,
    f4* __restrict__ tex)
{
    const int j = threadIdx.x;
    const int i = blockIdx.x;
    const int b = blockIdx.y;
    const float* __restrict__ z = z_grid + (size_t)b * (GH * GW);
    int ipu = (i < GH - 1) ? i + 1 : i;
    int imu = (i > 0) ? i - 1 : i;
    int jpv = (j < GW - 1) ? j + 1 : j;
    int jmv = (j > 0) ? j - 1 : j;
    float scu = (ipu - imu == 2) ? 0.5f : 1.0f;
    float scv = (jpv - jmv == 2) ? 0.5f : 1.0f;
    float gx = ((z[ipu * GW + j] - z[imu * GW + j]) * scu) * 10.0f;
    float gy = ((z[i * GW + jpv] - z[i * GW + jmv]) * scv) * 10.0f;
    f4 o;
    o.x = z[i * GW + j];
    o.y = gx;
    o.z = gy;
    o.w = friction[(size_t)b * (GH * GW) + i * GW + j];
    tex[(size_t)b * (GH * GW) + i * GW + j] = o;
}

// Prefetch phase for step TN: build A from (updated) W, compute next pts via
// R_t·(A·p) [associativity: (R·A)·p == R·(A·p) up to 1ulp], issue tex loads,
// THEN complete the full R = R·A update under the load latency.
#define PREFETCH(TN)                                                            \
do {                                                                            \
    cc = *(const f2*)(ct + (TN) * 2);                                           \
    float th2s = W0 * W0 + W1 * W1 + W2 * W2;                                   \
    float a2 = th2s * 1e-4f;                                                    \
    float s1 = 0.01f - a2 * (0.01f / 6.0f);                                     \
    float c2 = 5e-5f - a2 * (1e-4f / 24.0f);                                    \
    float w01p = W0 * W1, w02p = W0 * W2, w12p = W1 * W2;                       \
    float A00 = 1.0f - c2 * (W1 * W1 + W2 * W2);                                \
    float A11 = 1.0f - c2 * (W0 * W0 + W2 * W2);                                \
    float A22 = 1.0f - c2 * (W0 * W0 + W1 * W1);                                \
    float A01 = c2 * w01p - s1 * W2;                                            \
    float A10 = c2 * w01p + s1 * W2;                                            \
    float A02 = c2 * w02p + s1 * W1;                                            \
    float A20 = c2 * w02p - s1 * W1;                                            \
    float A12 = c2 * w12p - s1 * W0;                                            \
    float A21 = c2 * w12p + s1 * W0;                                            \
    float ap0 = A00 * ppx + A01 * ppy + A02 * ppz;                              \
    float ap1 = A10 * ppx + A11 * ppy + A12 * ppz;                              \
    float ap2 = A20 * ppx + A21 * ppy + A22 * ppz;                              \
    float rp0 = R00 * ap0 + R01 * ap1 + R02 * ap2;                              \
    float rp1 = R10 * ap0 + R11 * ap1 + R12 * ap2;                              \
    float rp2 = R20 * ap0 + R21 * ap1 + R22 * ap2;                              \
    Px = rp0 + X0; Py = rp1 + X1; Pz = rp2 + X2;                                \
    l0 = Px - X0; l1 = Py - X1; l2 = Pz - X2;                                   \
    float u_ = fminf(fmaxf((Px + 12.8f) * 10.0f, 0.0f), 254.999f);              \
    float v_ = fminf(fmaxf((Py + 12.8f) * 10.0f, 0.0f), 254.999f);              \
    int u0_ = (int)u_, v0_ = (int)v_;                                           \
    du = u_ - (float)u0_; dv = v_ - (float)v0_;                                 \
    int idx_ = (u0_ << 8) + v0_;                                                \
    c00 = tb[idx_];                                                             \
    c01 = tb[idx_ + 1];                                                         \
    c10 = tb[idx_ + GW];                                                        \
    c11 = tb[idx_ + GW + 1];                                                    \
    /* full R update (27 fma) hides under the loads just issued */              \
    float N00 = R00 * A00 + R01 * A10 + R02 * A20;                              \
    float N01 = R00 * A01 + R01 * A11 + R02 * A21;                              \
    float N02 = R00 * A02 + R01 * A12 + R02 * A22;                              \
    float N10 = R10 * A00 + R11 * A10 + R12 * A20;                              \
    float N11 = R10 * A01 + R11 * A11 + R12 * A21;                              \
    float N12 = R10 * A02 + R11 * A12 + R12 * A22;                              \
    float N20 = R20 * A00 + R21 * A10 + R22 * A20;                              \
    float N21 = R20 * A01 + R21 * A11 + R22 * A21;                              \
    float N22 = R20 * A02 + R21 * A12 + R22 * A22;                              \
    R00 = N00; R01 = N01; R02 = N02;                                            \
    R10 = N10; R11 = N11; R12 = N12;                                            \
    R20 = N20; R21 = N21; R22 = N22;                                            \
} while (0)

// One simulated step (rotated schedule: loads for TCUR already in flight).
#define STEP_BODY(TCUR, PH)                                                     \
do {                                                                            \
    const int par_ = (PH < 0) ? ((TCUR) & 1) : ((PH) & 1);                      \
    /* load-shadow work (uses state at TCUR; R already = R_TCUR) */             \
    float cv = cc.x, cw = cc.y;                                                 \
    float half_ = (cw * 0.6f) * 0.5f;                                           \
    float vLs = cv - half_, vRs = cv + half_;                                   \
    float xp0 = V0 + (W1 * l2 - W2 * l1);                                       \
    float xp1 = V1 + (W2 * l0 - W0 * l2);                                       \
    float xp2 = V2 + (W0 * l1 - W1 * l0);                                       \
    float cmd = isL ? vLs : vRs;                                                \
    float ct0 = cmd * R00 - xp0;                                                \
    float ct1 = cmd * R10 - xp1;                                                \
    float ct2 = cmd * R20 - xp2;                                                \
    float w00 = (1.0f - du) * (1.0f - dv);                                      \
    float w10 = du * (1.0f - dv);                                               \
    float w01 = (1.0f - du) * dv;                                               \
    float w11 = du * dv;                                                        \
    /* bilinear blend of {z, gx, gy, fr} */                                     \
    f4 cb = c00 * w00 + c10 * w10 + c01 * w01 + c11 * w11;                      \
    float zz = cb.x, gxs = cb.y, gys = cb.z, fr = cb.w;                         \
    float rn = frsq(gxs * gxs + gys * gys + 1.0f);                              \
    float nx = -gxs * rn, ny = -gys * rn, nzc = rn;                             \
    float dh = Pz - zz;                                                         \
    float ex = fexp2(dh * 14.426950408889634f);                                 \
    float ic = frcp(1.0f + ex);                                                 \
    float xdn = xp0 * nx + xp1 * ny + xp2 * nzc;                                \
    float mag = -(1000.0f * dh + 100.0f * xdn);                                 \
    float mic = mag * ic;                                                       \
    float m_abs = fabsf(mic);                                                   \
    float sl0 = fr * ct0, sl1 = fr * ct1, sl2 = fr * ct2;                       \
    float sdn = sl0 * nx + sl1 * ny + sl2 * nzc;                                \
    float st0 = sl0 - sdn * nx;                                                 \
    float st1 = sl1 - sdn * ny;                                                 \
    float st2 = sl2 - sdn * nzc;                                                \
    float g0 = mic * nx  + m_abs * st0;                                         \
    float g1 = mic * ny  + m_abs * st1;                                         \
    float g2 = mic * nzc + m_abs * st2;                                         \
    float q0 = l1 * g2 - l2 * g1;                                               \
    float q1 = l2 * g0 - l0 * g2;                                               \
    float q2 = l0 * g1 - l1 * g0;                                               \
    float stm = fmaxf(fmaxf(fabsf(st0), fabsf(st1)), fabsf(st2));               \
    float worst = fmaxf(stm, 1.0f) * m_abs;                                     \
    /* 8 pipelined DPP chains; own via readlane, other via LDS */               \
    float d_ic = wave_sum63(ic);                                                \
    float d_g0 = wave_sum63(g0), d_g1 = wave_sum63(g1), d_g2 = wave_sum63(g2);  \
    float d_q0 = wave_sum63(q0), d_q1 = wave_sum63(q1), d_q2 = wave_sum63(q2);  \
    float d_rw = wave_max63(worst);                                             \
    if ((tid & 63) == 63) {                                                     \
        f4l h0; h0.x = d_g0; h0.y = d_g1; h0.z = d_g2; h0.w = d_q0;             \
        f4l h1; h1.x = d_q1; h1.y = d_q2; h1.z = d_ic; h1.w = d_rw;             \
        ldsX[par_][wv][0] = h0; ldsX[par_][wv][1] = h1;                         \
    }                                                                           \
    float o_ic = rl63(d_ic);                                                    \
    float o_g0 = rl63(d_g0), o_g1 = rl63(d_g1), o_g2 = rl63(d_g2);              \
    float o_q0 = rl63(d_q0), o_q1 = rl63(d_q1), o_q2 = rl63(d_q2);              \
    float o_rw = rl63(d_rw);                                                    \
    LDS_BARRIER();                                                              \
    f4l e0 = ldsX[par_][wv ^ 1][0], e1 = ldsX[par_][wv ^ 1][1];                 \
    float sic = o_ic + e1.z;                                                    \
    float rwm = fmaxf(o_rw, e1.w);                                              \
    float rsic = frcp(sic);                                                     \
    float FT0, FT1, FT2, TQ0, TQ1, TQ2;                                         \
    if (rwm <= 391.0f * sic) {                                                  \
        FT0 = (o_g0 + e0.x) * rsic;                                             \
        FT1 = (o_g1 + e0.y) * rsic;                                             \
        FT2 = (o_g2 + e0.z) * rsic;                                             \
        TQ0 = (o_q0 + e0.w) * rsic;                                             \
        TQ1 = (o_q1 + e1.x) * rsic;                                             \
        TQ2 = (o_q2 + e1.y) * rsic;                                             \
    } else {                                                                    \
        float s = mic * rsic;                                                   \
        float Fr0 = fminf(fmaxf(s * nx,  -392.0f), 392.0f);                     \
        float Fr1 = fminf(fmaxf(s * ny,  -392.0f), 392.0f);                     \
        float Fr2 = fminf(fmaxf(s * nzc, -392.0f), 392.0f);                     \
        float Nm = __builtin_amdgcn_sqrtf(Fr0 * Fr0 + Fr1 * Fr1 + Fr2 * Fr2);   \
        float Ff0 = fminf(fmaxf(Nm * st0, -392.0f), 392.0f);                    \
        float Ff1 = fminf(fmaxf(Nm * st1, -392.0f), 392.0f);                    \
        float Ff2 = fminf(fmaxf(Nm * st2, -392.0f), 392.0f);                    \
        float S0 = Fr0 + Ff0, S1 = Fr1 + Ff1, S2 = Fr2 + Ff2;                   \
        float U0 = l1 * S2 - l2 * S1;                                           \
        float U1 = l2 * S0 - l0 * S2;                                           \
        float U2 = l0 * S1 - l1 * S0;                                           \
        float dS0 = wave_sum63(S0), dS1 = wave_sum63(S1), dS2 = wave_sum63(S2); \
        float dU0 = wave_sum63(U0), dU1 = wave_sum63(U1), dU2 = wave_sum63(U2); \
        if ((tid & 63) == 63) {                                                 \
            f4l h0; h0.x = dS0; h0.y = dS1; h0.z = dS2; h0.w = dU0;             \
            f4l h1; h1.x = dU1; h1.y = dU2; h1.z = 0.f; h1.w = 0.f;             \
            ldsY[wv][0] = h0; ldsY[wv][1] = h1;                                 \
        }                                                                       \
        LDS_BARRIER();                                                          \
        f4l c0 = ldsY[wv ^ 1][0], c1 = ldsY[wv ^ 1][1];                         \
        FT0 = rl63(dS0) + c0.x; FT1 = rl63(dS1) + c0.y; FT2 = rl63(dS2) + c0.z; \
        TQ0 = rl63(dU0) + c0.w; TQ1 = rl63(dU1) + c1.x; TQ2 = rl63(dU2) + c1.y; \
    }                                                                           \
    float od0 = fminf(fmaxf(TQ0 * i00 + TQ1 * i01 + TQ2 * i02, -2.0f), 2.0f);   \
    float od1 = fminf(fmaxf(TQ0 * i01 + TQ1 * i11 + TQ2 * i12, -2.0f), 2.0f);   \
    float od2 = fminf(fmaxf(TQ0 * i02 + TQ1 * i12 + TQ2 * i22, -2.0f), 2.0f);   \
    V0 += (FT0 * 0.025f) * 0.01f;                                               \
    V1 += (FT1 * 0.025f) * 0.01f;                                               \
    V2 += ((-392.0f + FT2) * 0.025f) * 0.01f;                                   \
    X0 += V0 * 0.01f; X1 += V1 * 0.01f; X2 += V2 * 0.01f;                       \
    W0 += od0 * 0.01f; W1 += od1 * 0.01f; W2 += od2 * 0.01f;                    \
    /* prefetch next step (issues tex loads; R update hides under them) */      \
    {                                                                           \
        int tn_ = ((TCUR) + 1 < T) ? (TCUR) + 1 : T - 1;                        \
        PREFETCH(tn_);                                                          \
    }                                                                           \
    if (PH < 0) {                                                               \
        if (tid == 0) {                                                         \
            ob[(TCUR) * 3 + 0] = X0;                                            \
            ob[(TCUR) * 3 + 1] = X1;                                            \
            ob[(TCUR) * 3 + 2] = X2;                                            \
        }                                                                       \
    } else if (PH == 0) { sb0.x = X0; sb0.y = X1; sb0.z = X2; }                 \
    else if (PH == 1) { sb0.w = X0; sb1.x = X1; sb1.y = X2; }                   \
    else if (PH == 2) { sb1.z = X0; sb1.w = X1; sb2.x = X2; }                   \
    else {                                                                      \
        sb2.y = X0; sb2.z = X1; sb2.w = X2;                                     \
        if (tid == 0) {                                                         \
            f4* op = (f4*)(ob + ((TCUR) - 3) * 3);                              \
            op[0] = sb0; op[1] = sb1; op[2] = sb2;                              \
        }                                                                       \
    }                                                                           \
} while (0)

// ---------- main sim kernel (texture path) ----------
__global__ __launch_bounds__(128) void dphys_kernel(
    const f4* __restrict__ tex,
    const float* __restrict__ controls,
    const float* __restrict__ robot_points,
    const float* __restrict__ x0,
    const float* __restrict__ xd0,
    const float* __restrict__ R0,
    const float* __restrict__ omega0,
    float* __restrict__ out,
    int T)
{
    const int b = blockIdx.x;
    const int tid = threadIdx.x;
    const int wv = tid >> 6;
    __shared__ f4l ldsX[2][2][2];
    __shared__ f4l ldsY[2][2];

    const f4* __restrict__ tb = tex + (size_t)b * (GH * GW);
    const float* __restrict__ ct = controls + (size_t)b * (T * 2);
    float* __restrict__ ob = out + (size_t)b * (T * 3);

    const float ppx = robot_points[tid * 3 + 0];
    const float ppy = robot_points[tid * 3 + 1];
    const float ppz = robot_points[tid * 3 + 2];
    const bool isL = (ppy < 0.0f);

    // inertia (one-time)
    float I6[6];
    I6[0] = ppy * ppy + ppz * ppz;
    I6[1] = ppx * ppx + ppz * ppz;
    I6[2] = ppx * ppx + ppy * ppy;
    I6[3] = ppx * ppy;
    I6[4] = ppx * ppz;
    I6[5] = ppy * ppz;
    #pragma unroll
    for (int k = 0; k < 6; ++k) I6[k] = rl63(wave_sum63(I6[k]));
    if ((tid & 63) == 63) {
        f4l t0; t0.x = I6[0]; t0.y = I6[1]; t0.z = I6[2]; t0.w = I6[3];
        f4l t1; t1.x = I6[4]; t1.y = I6[5]; t1.z = 0.f; t1.w = 0.f;
        ldsY[wv][0] = t0; ldsY[wv][1] = t1;
    }
    __syncthreads();
    {
        f4l o0 = ldsY[wv ^ 1][0], o1 = ldsY[wv ^ 1][1];
        I6[0] += o0.x; I6[1] += o0.y; I6[2] += o0.z;
        I6[3] += o0.w; I6[4] += o1.x; I6[5] += o1.y;
    }
    const float mp = 0.3125f;
    {
        double a = mp * I6[0], bb = mp * I6[1], c = mp * I6[2];
        double d = -(mp * I6[3]), e = -(mp * I6[4]), f = -(mp * I6[5]);
        double C00 = bb * c - f * f, C01 = e * f - d * c, C02 = d * f - bb * e;
        double C11 = a * c - e * e, C12 = d * e - a * f, C22 = a * bb - d * d;
        double idet = 1.0 / (a * C00 + d * C01 + e * C02);
        I6[0] = (float)(C00 * idet); I6[1] = (float)(C11 * idet); I6[2] = (float)(C22 * idet);
        I6[3] = (float)(C01 * idet); I6[4] = (float)(C02 * idet); I6[5] = (float)(C12 * idet);
    }
    const float i00 = I6[0], i11 = I6[1], i22 = I6[2];
    const float i01 = I6[3], i02 = I6[4], i12 = I6[5];

    float X0 = x0[b * 3 + 0], X1 = x0[b * 3 + 1], X2 = x0[b * 3 + 2];
    float V0 = xd0[b * 3 + 0], V1 = xd0[b * 3 + 1], V2 = xd0[b * 3 + 2];
    float W0 = omega0[b * 3 + 0], W1 = omega0[b * 3 + 1], W2 = omega0[b * 3 + 2];
    float R00 = R0[b * 9 + 0], R01 = R0[b * 9 + 1], R02 = R0[b * 9 + 2];
    float R10 = R0[b * 9 + 3], R11 = R0[b * 9 + 4], R12 = R0[b * 9 + 5];
    float R20 = R0[b * 9 + 6], R21 = R0[b * 9 + 7], R22 = R0[b * 9 + 8];

    f4 sb0, sb1, sb2;                 // 4-step output buffer
    f2 cc;                            // controls for current step
    float Px, Py, Pz, l0, l1, l2, du, dv;   // pipelined position/address state
    f4 c00, c01, c10, c11;            // pipelined texture loads

    // prologue: step-0 addresses + loads from R0, X0 directly
    cc = *(const f2*)(ct);
    {
        float rx = R00 * ppx + R01 * ppy + R02 * ppz;
        float ry = R10 * ppx + R11 * ppy + R12 * ppz;
        float rz = R20 * ppx + R21 * ppy + R22 * ppz;
        Px = rx + X0; Py = ry + X1; Pz = rz + X2;
        l0 = Px - X0; l1 = Py - X1; l2 = Pz - X2;
        float u_ = fminf(fmaxf((Px + 12.8f) * 10.0f, 0.0f), 254.999f);
        float v_ = fminf(fmaxf((Py + 12.8f) * 10.0f, 0.0f), 254.999f);
        int u0_ = (int)u_, v0_ = (int)v_;
        du = u_ - (float)u0_; dv = v_ - (float)v0_;
        int idx_ = (u0_ << 8) + v0_;
        c00 = tb[idx_]; c01 = tb[idx_ + 1]; c10 = tb[idx_ + GW]; c11 = tb[idx_ + GW + 1];
    }

    int t = 0;
    for (; t + 3 < T; t += 4) {
        STEP_BODY(t + 0, 0);
        STEP_BODY(t + 1, 1);
        STEP_BODY(t + 2, 2);
        STEP_BODY(t + 3, 3);
    }
    for (; t < T; ++t) {
        STEP_BODY(t, -1);
    }
}

// ---------- fallback (no-workspace path; R7/R8 structure) ----------
__global__ __launch_bounds__(128) void dphys_kernel_fb(
    const float* __restrict__ z_grid,
    const float* __restrict__ friction,
    const float* __restrict__ controls,
    const float* __restrict__ robot_points,
    const float* __restrict__ x0,
    const float* __restrict__ xd0,
    const float* __restrict__ R0,
    const float* __restrict__ omega0,
    float* __restrict__ out,
    int T)
{
    const int b = blockIdx.x;
    const int tid = threadIdx.x;
    const int wv = tid >> 6;
    __shared__ f4l ldsX[2][2][2];
    __shared__ f4l ldsY[2][2];

    const float* __restrict__ zg = z_grid + (size_t)b * (GH * GW);
    const float* __restrict__ fg = friction + (size_t)b * (GH * GW);
    const float* __restrict__ ct = controls + (size_t)b * (T * 2);
    float* __restrict__ ob = out + (size_t)b * (T * 3);

    const float ppx = robot_points[tid * 3 + 0];
    const float ppy = robot_points[tid * 3 + 1];
    const float ppz = robot_points[tid * 3 + 2];
    const bool isL = (ppy < 0.0f);

    float I6[6];
    I6[0] = ppy * ppy + ppz * ppz;
    I6[1] = ppx * ppx + ppz * ppz;
    I6[2] = ppx * ppx + ppy * ppy;
    I6[3] = ppx * ppy;
    I6[4] = ppx * ppz;
    I6[5] = ppy * ppz;
    #pragma unroll
    for (int k = 0; k < 6; ++k) I6[k] = rl63(wave_sum63(I6[k]));
    if ((tid & 63) == 63) {
        f4l t0; t0.x = I6[0]; t0.y = I6[1]; t0.z = I6[2]; t0.w = I6[3];
        f4l t1; t1.x = I6[4]; t1.y = I6[5]; t1.z = 0.f; t1.w = 0.f;
        ldsY[wv][0] = t0; ldsY[wv][1] = t1;
    }
    __syncthreads();
    {
        f4l o0 = ldsY[wv ^ 1][0], o1 = ldsY[wv ^ 1][1];
        I6[0] += o0.x; I6[1] += o0.y; I6[2] += o0.z;
        I6[3] += o0.w; I6[4] += o1.x; I6[5] += o1.y;
    }
    const float mp = 0.3125f;
    {
        double a = mp * I6[0], bb = mp * I6[1], c = mp * I6[2];
        double d = -(mp * I6[3]), e = -(mp * I6[4]), f = -(mp * I6[5]);
        double C00 = bb * c - f * f, C01 = e * f - d * c, C02 = d * f - bb * e;
        double C11 = a * c - e * e, C12 = d * e - a * f, C22 = a * bb - d * d;
        double idet = 1.0 / (a * C00 + d * C01 + e * C02);
        I6[0] = (float)(C00 * idet); I6[1] = (float)(C11 * idet); I6[2] = (float)(C22 * idet);
        I6[3] = (float)(C01 * idet); I6[4] = (float)(C02 * idet); I6[5] = (float)(C12 * idet);
    }
    const float i00 = I6[0], i11 = I6[1], i22 = I6[2];
    const float i01 = I6[3], i02 = I6[4], i12 = I6[5];

    float X0 = x0[b * 3 + 0], X1 = x0[b * 3 + 1], X2 = x0[b * 3 + 2];
    float V0 = xd0[b * 3 + 0], V1 = xd0[b * 3 + 1], V2 = xd0[b * 3 + 2];
    float W0 = omega0[b * 3 + 0], W1 = omega0[b * 3 + 1], W2 = omega0[b * 3 + 2];
    float R00 = R0[b * 9 + 0], R01 = R0[b * 9 + 1], R02 = R0[b * 9 + 2];
    float R10 = R0[b * 9 + 3], R11 = R0[b * 9 + 4], R12 = R0[b * 9 + 5];
    float R20 = R0[b * 9 + 6], R21 = R0[b * 9 + 7], R22 = R0[b * 9 + 8];

    for (int t = 0; t < T; ++t) {
        const int par = t & 1;
        f2 cc = *(const f2*)(ct + t * 2);
        float rx = R00 * ppx + R01 * ppy + R02 * ppz;
        float ry = R10 * ppx + R11 * ppy + R12 * ppz;
        float rz = R20 * ppx + R21 * ppy + R22 * ppz;
        float Px = rx + X0, Py = ry + X1, Pz = rz + X2;
        float l0 = Px - X0, l1 = Py - X1, l2 = Pz - X2;
        float u = fminf(fmaxf((Px + 12.8f) * 10.0f, 0.0f), 254.999f);
        float vvq = fminf(fmaxf((Py + 12.8f) * 10.0f, 0.0f), 254.999f);
        int u0 = (int)u, v0 = (int)vvq;
        bool interior = (u0 >= 1) & (u0 <= 253) & (v0 >= 1) & (v0 <= 253);
        bool fastp = __all(interior);

        float zz, fr, gxs, gys;
        float du = u - (float)u0, dv = vvq - (float)v0;
        float w00 = (1.0f - du) * (1.0f - dv);
        float w10 = du * (1.0f - dv);
        float w01 = (1.0f - du) * dv;
        float w11 = du * dv;

        float cv = cc.x, cw = cc.y;
        float half = (cw * 0.6f) * 0.5f;
        float vLs = cv - half, vRs = cv + half;
        float rtn = frsq(R00 * R00 + R10 * R10 + R20 * R20);
        float th0 = R00 * rtn, th1 = R10 * rtn, th2 = R20 * rtn;
        float xp0 = V0 + (W1 * l2 - W2 * l1);
        float xp1 = V1 + (W2 * l0 - W0 * l2);
        float xp2 = V2 + (W0 * l1 - W1 * l0);
        float cmd = isL ? vLs : vRs;
        float ct0 = cmd * th0 - xp0;
        float ct1 = cmd * th1 - xp1;
        float ct2 = cmd * th2 - xp2;

        if (fastp) {
            int base = (u0 - 1) * GW + (v0 - 1);
            f4 P0 = *(const f4*)(zg + base);
            f4 P1 = *(const f4*)(zg + base + GW);
            f4 P2 = *(const f4*)(zg + base + 2 * GW);
            f4 P3 = *(const f4*)(zg + base + 3 * GW);
            int fb = u0 * GW + v0;
            f2 F0 = *(const f2*)(fg + fb);
            f2 F1 = *(const f2*)(fg + fb + GW);
            zz = P1.y * w00 + P2.y * w10 + P1.z * w01 + P2.z * w11;
            fr = F0.x * w00 + F1.x * w10 + F0.y * w01 + F1.y * w11;
            float gx00 = (P2.y - P0.y) * 5.0f;
            float gx10 = (P3.y - P1.y) * 5.0f;
            float gx01 = (P2.z - P0.z) * 5.0f;
            float gx11 = (P3.z - P1.z) * 5.0f;
            float gy00 = (P1.z - P1.x) * 5.0f;
            float gy10 = (P2.z - P2.x) * 5.0f;
            float gy01 = (P1.w - P1.y) * 5.0f;
            float gy11 = (P2.w - P2.y) * 5.0f;
            gxs = gx00 * w00 + gx10 * w10 + gx01 * w01 + gx11 * w11;
            gys = gy00 * w00 + gy10 * w10 + gy01 * w01 + gy11 * w11;
        } else {
            int basei = u0 * GW + v0;
            zz = zg[basei] * w00 + zg[basei + GW] * w10 + zg[basei + 1] * w01 + zg[basei + GW + 1] * w11;
            fr = fg[basei] * w00 + fg[basei + GW] * w10 + fg[basei + 1] * w01 + fg[basei + GW + 1] * w11;
            float gx[2][2], gy[2][2];
            #pragma unroll
            for (int ii = 0; ii < 2; ++ii) {
                int i = u0 + ii;
                int ipu = (i < GH - 1) ? i + 1 : i;
                int imu = (i > 0) ? i - 1 : i;
                float scu = (ipu - imu == 2) ? 0.5f : 1.0f;
                #pragma unroll
                for (int jj = 0; jj < 2; ++jj) {
                    int j = v0 + jj;
                    int jpv = (j < GW - 1) ? j + 1 : j;
                    int jmv = (j > 0) ? j - 1 : j;
                    float scv = (jpv - jmv == 2) ? 0.5f : 1.0f;
                    gx[ii][jj] = ((zg[ipu * GW + j] - zg[imu * GW + j]) * scu) * 10.0f;
                    gy[ii][jj] = ((zg[i * GW + jpv] - zg[i * GW + jmv]) * scv) * 10.0f;
                }
            }
            gxs = gx[0][0] * w00 + gx[1][0] * w10 + gx[0][1] * w01 + gx[1][1] * w11;
            gys = gy[0][0] * w00 + gy[1][0] * w10 + gy[0][1] * w01 + gy[1][1] * w11;
        }

        float rn = frsq(gxs * gxs + gys * gys + 1.0f);
        float nx = -gxs * rn, ny = -gys * rn, nzc = rn;
        float dh = Pz - zz;
        float ex = fexp2(dh * 14.426950408889634f);
        float ic = frcp(1.0f + ex);
        float xdn = xp0 * nx + xp1 * ny + xp2 * nzc;

        float mag = -(1000.0f * dh + 100.0f * xdn);
        float mic = mag * ic;
        float m_abs = fabsf(mic);
        float sl0 = fr * ct0, sl1 = fr * ct1, sl2 = fr * ct2;
        float sdn = sl0 * nx + sl1 * ny + sl2 * nzc;
        float st0 = sl0 - sdn * nx;
        float st1 = sl1 - sdn * ny;
        float st2 = sl2 - sdn * nzc;
        float g0 = mic * nx  + m_abs * st0;
        float g1 = mic * ny  + m_abs * st1;
        float g2 = mic * nzc + m_abs * st2;
        float q0 = l1 * g2 - l2 * g1;
        float q1 = l2 * g0 - l0 * g2;
        float q2 = l0 * g1 - l1 * g0;
        float stm = fmaxf(fmaxf(fabsf(st0), fabsf(st1)), fabsf(st2));
        float worst = fmaxf(stm, 1.0f) * m_abs;

        float d_ic = wave_sum63(ic);
        float d_g0 = wave_sum63(g0), d_g1 = wave_sum63(g1), d_g2 = wave_sum63(g2);
        float d_q0 = wave_sum63(q0), d_q1 = wave_sum63(q1), d_q2 = wave_sum63(q2);
        float d_rw = wave_max63(worst);
        if ((tid & 63) == 63) {
            f4l h0; h0.x = d_g0; h0.y = d_g1; h0.z = d_g2; h0.w = d_q0;
            f4l h1; h1.x = d_q1; h1.y = d_q2; h1.z = d_ic; h1.w = d_rw;
            ldsX[par][wv][0] = h0; ldsX[par][wv][1] = h1;
        }
        float o_ic = rl63(d_ic);
        float o_g0 = rl63(d_g0), o_g1 = rl63(d_g1), o_g2 = rl63(d_g2);
        float o_q0 = rl63(d_q0), o_q1 = rl63(d_q1), o_q2 = rl63(d_q2);
        float o_rw = rl63(d_rw);
        __syncthreads();
        f4l e0 = ldsX[par][wv ^ 1][0], e1 = ldsX[par][wv ^ 1][1];
        float sic = o_ic + e1.z;
        float rwm = fmaxf(o_rw, e1.w);
        float rsic = frcp(sic);

        float FT0, FT1, FT2, TQ0, TQ1, TQ2;
        if (rwm <= 391.0f * sic) {
            FT0 = (o_g0 + e0.x) * rsic;
            FT1 = (o_g1 + e0.y) * rsic;
            FT2 = (o_g2 + e0.z) * rsic;
            TQ0 = (o_q0 + e0.w) * rsic;
            TQ1 = (o_q1 + e1.x) * rsic;
            TQ2 = (o_q2 + e1.y) * rsic;
        } else {
            float s = mic * rsic;
            float Fr0 = fminf(fmaxf(s * nx,  -392.0f), 392.0f);
            float Fr1 = fminf(fmaxf(s * ny,  -392.0f), 392.0f);
            float Fr2 = fminf(fmaxf(s * nzc, -392.0f), 392.0f);
            float Nm = __builtin_amdgcn_sqrtf(Fr0 * Fr0 + Fr1 * Fr1 + Fr2 * Fr2);
            float Ff0 = fminf(fmaxf(Nm * st0, -392.0f), 392.0f);
            float Ff1 = fminf(fmaxf(Nm * st1, -392.0f), 392.0f);
            float Ff2 = fminf(fmaxf(Nm * st2, -392.0f), 392.0f);
            float S0 = Fr0 + Ff0, S1 = Fr1 + Ff1, S2 = Fr2 + Ff2;
            float U0 = l1 * S2 - l2 * S1;
            float U1 = l2 * S0 - l0 * S2;
            float U2 = l0 * S1 - l1 * S0;
            float dS0 = wave_sum63(S0), dS1 = wave_sum63(S1), dS2 = wave_sum63(S2);
            float dU0 = wave_sum63(U0), dU1 = wave_sum63(U1), dU2 = wave_sum63(U2);
            if ((tid & 63) == 63) {
                f4l h0; h0.x = dS0; h0.y = dS1; h0.z = dS2; h0.w = dU0;
                f4l h1; h1.x = dU1; h1.y = dU2; h1.z = 0.f; h1.w = 0.f;
                ldsY[wv][0] = h0; ldsY[wv][1] = h1;
            }
            __syncthreads();
            f4l c0 = ldsY[wv ^ 1][0], c1 = ldsY[wv ^ 1][1];
            FT0 = rl63(dS0) + c0.x; FT1 = rl63(dS1) + c0.y; FT2 = rl63(dS2) + c0.z;
            TQ0 = rl63(dU0) + c0.w; TQ1 = rl63(dU1) + c1.x; TQ2 = rl63(dU2) + c1.y;
        }

        float od0 = fminf(fmaxf(TQ0 * i00 + TQ1 * i01 + TQ2 * i02, -2.0f), 2.0f);
        float od1 = fminf(fmaxf(TQ0 * i01 + TQ1 * i11 + TQ2 * i12, -2.0f), 2.0f);
        float od2 = fminf(fmaxf(TQ0 * i02 + TQ1 * i12 + TQ2 * i22, -2.0f), 2.0f);

        V0 += (FT0 * 0.025f) * 0.01f;
        V1 += (FT1 * 0.025f) * 0.01f;
        V2 += ((-392.0f + FT2) * 0.025f) * 0.01f;
        X0 += V0 * 0.01f; X1 += V1 * 0.01f; X2 += V2 * 0.01f;
        W0 += od0 * 0.01f; W1 += od1 * 0.01f; W2 += od2 * 0.01f;

        if (tid == 0) {
            ob[t * 3 + 0] = X0;
            ob[t * 3 + 1] = X1;
            ob[t * 3 + 2] = X2;
        }

        float th2s = W0 * W0 + W1 * W1 + W2 * W2;
        float a2 = th2s * 1e-4f;
        float s1 = 0.01f - a2 * (0.01f / 6.0f);
        float c2 = 5e-5f - a2 * (1e-4f / 24.0f);
        float w01p = W0 * W1, w02p = W0 * W2, w12p = W1 * W2;
        float A00 = 1.0f - c2 * (W1 * W1 + W2 * W2);
        float A11 = 1.0f - c2 * (W0 * W0 + W2 * W2);
        float A22 = 1.0f - c2 * (W0 * W0 + W1 * W1);
        float A01 = c2 * w01p - s1 * W2;
        float A10 = c2 * w01p + s1 * W2;
        float A02 = c2 * w02p + s1 * W1;
        float A20 = c2 * w02p - s1 * W1;
        float A12 = c2 * w12p - s1 * W0;
        float A21 = c2 * w12p + s1 * W0;
        float N00 = R00 * A00 + R01 * A10 + R02 * A20;
        float N01 = R00 * A01 + R01 * A11 + R02 * A21;
        float N02 = R00 * A02 + R01 * A12 + R02 * A22;
        float N10 = R10 * A00 + R11 * A10 + R12 * A20;
        float N11 = R10 * A01 + R11 * A11 + R12 * A21;
        float N12 = R10 * A02 + R11 * A12 + R12 * A22;
        float N20 = R20 * A00 + R21 * A10 + R22 * A20;
        float N21 = R20 * A01 + R21 * A11 + R22 * A21;
        float N22 = R20 * A02 + R21 * A12 + R22 * A22;
        R00 = N00; R01 = N01; R02 = N02;
        R10 = N10; R11 = N11; R12 = N12;
        R20 = N20; R21 = N21; R22 = N22;
    }
}

extern "C" void kernel_launch(void* const* d_in, const int* in_sizes, int n_in,
                              void* d_out, int out_size, void* d_ws, size_t ws_size,
                              hipStream_t stream) {
    const float* z_grid       = (const float*)d_in[0];
    const float* friction     = (const float*)d_in[1];
    const float* controls     = (const float*)d_in[2];
    const float* robot_points = (const float*)d_in[3];
    const float* x0           = (const float*)d_in[4];
    const float* xd0          = (const float*)d_in[5];
    const float* R0           = (const float*)d_in[6];
    const float* omega0       = (const float*)d_in[7];
    int B = in_sizes[4] / 3;                 // 64
    int T = in_sizes[2] / (B * 2);           // 500
    size_t need = (size_t)B * GH * GW * sizeof(float) * 4;
    if (ws_size >= need) {
        prep_kernel<<<dim3(GH, B), GW, 0, stream>>>(z_grid, friction, (f4*)d_ws);
        dphys_kernel<<<B, 128, 0, stream>>>((const f4*)d_ws, controls, robot_points,
                                            x0, xd0, R0, omega0, (float*)d_out, T);
    } else {
        dphys_kernel_fb<<<B, 128, 0, stream>>>(z_grid, friction, controls, robot_points,
                                               x0, xd0, R0, omega0, (float*)d_out, T);
    }
}